// Round 1
// baseline (4901.568 us; speedup 1.0000x reference)
//
#include <hip/hip_runtime.h>
#include <stdint.h>

#define N_NODES 40000
#define N_EDGES 1280000

// ---------- helpers ----------
__device__ __forceinline__ float fast_silu(float x) {
    // silu(x) = x * sigmoid(x); __expf -> v_exp_f32, rcp approx (rel err ~1e-6)
    float e = __expf(-x);
    return x * __builtin_amdgcn_rcpf(1.0f + e);
}

__device__ __forceinline__ unsigned int pack_bf2(float a, float b) {
    // round-to-nearest-even bf16 pair packed into one uint (a = low half / even index)
    unsigned int ua = __float_as_uint(a);
    unsigned int ub = __float_as_uint(b);
    ua = (ua + 0x7FFFu + ((ua >> 16) & 1u)) >> 16;
    ub = (ub + 0x7FFFu + ((ub >> 16) & 1u)) & 0xFFFF0000u;
    return (ua & 0xFFFFu) | ub;
}

__device__ __forceinline__ float bf16_to_f(unsigned short s) {
    return __uint_as_float(((unsigned int)s) << 16);
}

// ---------- edge kernel ----------
// 256 edges / block (4 waves, lane = edge). LDS:
//   e_lds  : ushort [256][130]  (k=0..63 h[row], k=64..127 h[col]) -- 66560 B
//            per-wave overlay: float [64][65] scratch for m round-trips
//   rad/dif/msk/ri/ci : small per-edge arrays
// total ~73.7 KB -> 2 blocks/CU.
__global__ __launch_bounds__(256, 2) void egcl_edge_kernel(
    const float* __restrict__ h, const float* __restrict__ coord,
    const int* __restrict__ eidx, const float* __restrict__ emask,
    const float* __restrict__ We1, const float* __restrict__ be1,
    const float* __restrict__ We2, const float* __restrict__ be2,
    const float* __restrict__ Wc1, const float* __restrict__ bc1,
    const float* __restrict__ Wc2,
    float* __restrict__ agg, float* __restrict__ aggc, float* __restrict__ cnt)
{
    __shared__ unsigned short e_lds[256 * 130];
    __shared__ float rad_lds[256];
    __shared__ float dif_lds[256 * 3];
    __shared__ float msk_lds[256];
    __shared__ int   ri_lds[256];
    __shared__ int   ci_lds[256];

    const int t = threadIdx.x;
    const int ebase = blockIdx.x * 256;

    // phase 0: one edge per thread -> indices, coord diff, radial, mask
    {
        const int e = ebase + t;
        const int r = eidx[e];
        const int c = eidx[N_EDGES + e];
        ri_lds[t] = r;
        ci_lds[t] = c;
        const float crx = coord[(size_t)r * 3 + 0];
        const float cry = coord[(size_t)r * 3 + 1];
        const float crz = coord[(size_t)r * 3 + 2];
        const float ccx = coord[(size_t)c * 3 + 0];
        const float ccy = coord[(size_t)c * 3 + 1];
        const float ccz = coord[(size_t)c * 3 + 2];
        const float d0 = crx - ccx, d1 = cry - ccy, d2 = crz - ccz;
        dif_lds[t * 3 + 0] = d0;
        dif_lds[t * 3 + 1] = d1;
        dif_lds[t * 3 + 2] = d2;
        rad_lds[t] = d0 * d0 + d1 * d1 + d2 * d2;
        msk_lds[t] = emask[e];
    }
    __syncthreads();

    // phase 1: stage h[row], h[col] rows as bf16 (16 threads per edge, float4 loads)
    unsigned int* e32 = (unsigned int*)e_lds;
    for (int idx = t; idx < 256 * 16; idx += 256) {
        const int le = idx >> 4;
        const int part = idx & 15;
        const int r = ri_lds[le];
        const int c = ci_lds[le];
        const float4 vr = *(const float4*)(h + (size_t)r * 64 + part * 4);
        const float4 vc = *(const float4*)(h + (size_t)c * 64 + part * 4);
        const int b = le * 65 + part * 2;        // uint index; row stride 65 uints (=130 ushorts)
        e32[b + 0]  = pack_bf2(vr.x, vr.y);
        e32[b + 1]  = pack_bf2(vr.z, vr.w);
        e32[b + 32] = pack_bf2(vc.x, vc.y);      // h[col] at k = 64..127
        e32[b + 33] = pack_bf2(vc.z, vc.w);
    }
    __syncthreads();

    // phase 2: per-lane MLP chain (lane = edge)
    const int wave = t >> 6;
    const int lane = t & 63;
    const unsigned short* my_e = e_lds + t * 130;
    float* my_m = ((float*)(e_lds + wave * 64 * 130)) + lane * 65;  // per-lane 65-float scratch (overlays own row)
    const float radial = rad_lds[t];

    float acc[64];
    // --- edge layer 1: [129]x[129,64], radial term folded into init ---
    #pragma unroll
    for (int c = 0; c < 64; c++) acc[c] = fmaf(radial, We1[128 * 64 + c], be1[c]);
    for (int k = 0; k < 128; k++) {
        const float ek = bf16_to_f(my_e[k]);
        const float* __restrict__ w = We1 + k * 64;   // uniform -> SGPR broadcast
        #pragma unroll
        for (int c = 0; c < 64; c++) acc[c] = fmaf(ek, w[c], acc[c]);
    }
    #pragma unroll
    for (int c = 0; c < 64; c++) my_m[c] = fast_silu(acc[c]);   // m1 -> LDS (done reading my_e)

    // --- edge layer 2 ---
    #pragma unroll
    for (int c = 0; c < 64; c++) acc[c] = be2[c];
    for (int k = 0; k < 64; k++) {
        const float mk = my_m[k];
        const float* __restrict__ w = We2 + k * 64;
        #pragma unroll
        for (int c = 0; c < 64; c++) acc[c] = fmaf(mk, w[c], acc[c]);
    }
    const float mask = msk_lds[t];
    #pragma unroll
    for (int c = 0; c < 64; c++) acc[c] = fast_silu(acc[c]) * mask;   // m (masked)

    // stash m for coord-mlp, scatter-add into agg[row]
    #pragma unroll
    for (int c = 0; c < 64; c++) my_m[c] = acc[c];
    const int r = ri_lds[t];
    float* aggrow = agg + (size_t)r * 64;
    #pragma unroll
    for (int c = 0; c < 64; c++) atomicAdd(aggrow + c, acc[c]);

    // --- coord mlp: silu(m@Wc1+bc1)@Wc2 ---
    #pragma unroll
    for (int c = 0; c < 64; c++) acc[c] = bc1[c];
    for (int k = 0; k < 64; k++) {
        const float mk = my_m[k];
        const float* __restrict__ w = Wc1 + k * 64;
        #pragma unroll
        for (int c = 0; c < 64; c++) acc[c] = fmaf(mk, w[c], acc[c]);
    }
    float cval = 0.0f;
    #pragma unroll
    for (int k = 0; k < 64; k++) cval = fmaf(fast_silu(acc[k]), Wc2[k], cval);
    cval *= mask;   // trans = coord_diff * c * edge_mask

    const float tx = dif_lds[t * 3 + 0] * cval;
    const float ty = dif_lds[t * 3 + 1] * cval;
    const float tz = dif_lds[t * 3 + 2] * cval;
    atomicAdd(aggc + (size_t)r * 3 + 0, tx);
    atomicAdd(aggc + (size_t)r * 3 + 1, ty);
    atomicAdd(aggc + (size_t)r * 3 + 2, tz);
    atomicAdd(cnt + r, 1.0f);
}

// ---------- node kernel ----------
__global__ __launch_bounds__(256, 2) void egcl_node_kernel(
    const float* __restrict__ h, const float* __restrict__ agg,
    const float* __restrict__ Wn1, const float* __restrict__ bn1,
    const float* __restrict__ Wn2, const float* __restrict__ bn2,
    float* __restrict__ hout)
{
    __shared__ unsigned short n_lds[256 * 130];
    const int t = threadIdx.x;
    const int nbase = blockIdx.x * 256;

    unsigned int* n32 = (unsigned int*)n_lds;
    for (int idx = t; idx < 256 * 16; idx += 256) {
        const int ln = idx >> 4;
        const int part = idx & 15;
        const int node = nbase + ln;
        float4 vh = make_float4(0.f, 0.f, 0.f, 0.f);
        float4 va = make_float4(0.f, 0.f, 0.f, 0.f);
        if (node < N_NODES) {
            vh = *(const float4*)(h + (size_t)node * 64 + part * 4);
            va = *(const float4*)(agg + (size_t)node * 64 + part * 4);
        }
        const int b = ln * 65 + part * 2;
        n32[b + 0]  = pack_bf2(vh.x, vh.y);
        n32[b + 1]  = pack_bf2(vh.z, vh.w);
        n32[b + 32] = pack_bf2(va.x, va.y);
        n32[b + 33] = pack_bf2(va.z, va.w);
    }
    __syncthreads();

    const int node = nbase + t;
    if (node >= N_NODES) return;

    const int wave = t >> 6;
    const int lane = t & 63;
    const unsigned short* my_n = n_lds + t * 130;
    float* my_m = ((float*)(n_lds + wave * 64 * 130)) + lane * 65;

    float acc[64];
    #pragma unroll
    for (int c = 0; c < 64; c++) acc[c] = bn1[c];
    for (int k = 0; k < 128; k++) {
        const float nk = bf16_to_f(my_n[k]);
        const float* __restrict__ w = Wn1 + k * 64;
        #pragma unroll
        for (int c = 0; c < 64; c++) acc[c] = fmaf(nk, w[c], acc[c]);
    }
    #pragma unroll
    for (int c = 0; c < 64; c++) my_m[c] = fast_silu(acc[c]);

    #pragma unroll
    for (int c = 0; c < 64; c++) acc[c] = bn2[c];
    for (int k = 0; k < 64; k++) {
        const float mk = my_m[k];
        const float* __restrict__ w = Wn2 + k * 64;
        #pragma unroll
        for (int c = 0; c < 64; c++) acc[c] = fmaf(mk, w[c], acc[c]);
    }

    float* orow = hout + (size_t)node * 64;
    #pragma unroll
    for (int c = 0; c < 16; c++) {
        float4 v = make_float4(acc[4 * c + 0], acc[4 * c + 1], acc[4 * c + 2], acc[4 * c + 3]);
        *(float4*)(orow + 4 * c) = v;
    }
}

// ---------- coord output kernel ----------
__global__ void egcl_coord_kernel(const float* __restrict__ coord,
                                  const float* __restrict__ aggc,
                                  const float* __restrict__ cnt,
                                  float* __restrict__ cout)
{
    const int i = blockIdx.x * 256 + threadIdx.x;
    if (i < N_NODES * 3) {
        const int node = i / 3;
        const float c = cnt[node];
        cout[i] = coord[i] + aggc[i] * __builtin_amdgcn_rcpf(fmaxf(c, 1.0f));
    }
}

// ---------- launch ----------
extern "C" void kernel_launch(void* const* d_in, const int* in_sizes, int n_in,
                              void* d_out, int out_size, void* d_ws, size_t ws_size,
                              hipStream_t stream)
{
    const float* h     = (const float*)d_in[0];
    const float* coord = (const float*)d_in[1];
    const int*   eidx  = (const int*)d_in[2];
    const float* emask = (const float*)d_in[3];
    const float* We1   = (const float*)d_in[4];
    const float* be1   = (const float*)d_in[5];
    const float* We2   = (const float*)d_in[6];
    const float* be2   = (const float*)d_in[7];
    const float* Wn1   = (const float*)d_in[8];
    const float* bn1   = (const float*)d_in[9];
    const float* Wn2   = (const float*)d_in[10];
    const float* bn2   = (const float*)d_in[11];
    const float* Wc1   = (const float*)d_in[12];
    const float* bc1   = (const float*)d_in[13];
    const float* Wc2   = (const float*)d_in[14];

    float* hout = (float*)d_out;                       // [N,64]
    float* cout = hout + (size_t)N_NODES * 64;         // [N,3]

    float* agg  = (float*)d_ws;                        // [N,64]
    float* aggc = agg + (size_t)N_NODES * 64;          // [N,3]
    float* cnt  = aggc + (size_t)N_NODES * 3;          // [N]

    // zero the accumulators (ws is poisoned 0xAA before every launch)
    hipMemsetAsync(d_ws, 0, (size_t)(N_NODES * 64 + N_NODES * 3 + N_NODES) * sizeof(float), stream);

    egcl_edge_kernel<<<N_EDGES / 256, 256, 0, stream>>>(
        h, coord, eidx, emask, We1, be1, We2, be2, Wc1, bc1, Wc2, agg, aggc, cnt);
    egcl_node_kernel<<<(N_NODES + 255) / 256, 256, 0, stream>>>(
        h, agg, Wn1, bn1, Wn2, bn2, hout);
    egcl_coord_kernel<<<(N_NODES * 3 + 255) / 256, 256, 0, stream>>>(
        coord, aggc, cnt, cout);
}

// Round 2
// 1342.441 us; speedup vs baseline: 3.6512x; 3.6512x over previous
//
#include <hip/hip_runtime.h>
#include <stdint.h>

#define N_NODES 40000
#define N_EDGES 1280000

// ---------- helpers ----------
__device__ __forceinline__ float fast_silu(float x) {
    float e = __expf(-x);
    return x * __builtin_amdgcn_rcpf(1.0f + e);
}

__device__ __forceinline__ unsigned int pack_bf2(float a, float b) {
    // round-to-nearest-even bf16 pair packed into one uint (a = low half / even index)
    unsigned int ua = __float_as_uint(a);
    unsigned int ub = __float_as_uint(b);
    ua = (ua + 0x7FFFu + ((ua >> 16) & 1u)) >> 16;
    ub = (ub + 0x7FFFu + ((ub >> 16) & 1u)) & 0xFFFF0000u;
    return (ua & 0xFFFFu) | ub;
}

__device__ __forceinline__ float bf16_to_f(unsigned short s) {
    return __uint_as_float(((unsigned int)s) << 16);
}

// ============================================================================
// FAST PATH: CSR-gather aggregation (no fp32 scatter atomics)
// ============================================================================

// --- histogram of row indices ---
__global__ void hist_kernel(const int* __restrict__ eidx, int* __restrict__ hist) {
    const int e = blockIdx.x * 256 + threadIdx.x;
    if (e < N_EDGES) atomicAdd(&hist[eidx[e]], 1);
}

// --- single-block exclusive scan over hist[N_NODES] -> offs, pos ---
__global__ __launch_bounds__(1024) void scan_kernel(const int* __restrict__ hist,
                                                    int* __restrict__ offs,
                                                    int* __restrict__ pos) {
    __shared__ int wtot[16];
    __shared__ int carry_s;
    const int t = threadIdx.x;
    const int wave = t >> 6, lane = t & 63;
    if (t == 0) carry_s = 0;
    __syncthreads();
    for (int base = 0; base < N_NODES; base += 1024) {
        const int idx = base + t;
        int orig = (idx < N_NODES) ? hist[idx] : 0;
        int v = orig;
        #pragma unroll
        for (int d = 1; d < 64; d <<= 1) {
            int u = __shfl_up(v, d, 64);
            if (lane >= d) v += u;
        }
        if (lane == 63) wtot[wave] = v;
        __syncthreads();
        if (wave == 0 && lane < 16) {
            int w = wtot[lane];
            #pragma unroll
            for (int d = 1; d < 16; d <<= 1) {
                int u = __shfl_up(w, d, 64);
                if (lane >= d) w += u;
            }
            wtot[lane] = w;
        }
        __syncthreads();
        const int wbase = (wave == 0) ? 0 : wtot[wave - 1];
        const int c = carry_s;
        const int excl = c + wbase + v - orig;
        if (idx < N_NODES) { offs[idx] = excl; pos[idx] = excl; }
        __syncthreads();   // all reads of carry_s / wtot done
        if (t == 0) carry_s = c + wtot[15];
        __syncthreads();
    }
}

// --- scatter edge ids into row-grouped order ---
__global__ void scatter_kernel(const int* __restrict__ eidx,
                               int* __restrict__ pos, int* __restrict__ edge_order) {
    const int e = blockIdx.x * 256 + threadIdx.x;
    if (e < N_EDGES) {
        const int r = eidx[e];
        const int slot = atomicAdd(&pos[r], 1);
        edge_order[slot] = e;
    }
}

// --- edge kernel: MLP chain, writes m (bf16) and trans (fp32) densely ---
__global__ __launch_bounds__(256, 2) void egcl_edge_kernel(
    const float* __restrict__ h, const float* __restrict__ coord,
    const int* __restrict__ eidx, const float* __restrict__ emask,
    const float* __restrict__ We1, const float* __restrict__ be1,
    const float* __restrict__ We2, const float* __restrict__ be2,
    const float* __restrict__ Wc1, const float* __restrict__ bc1,
    const float* __restrict__ Wc2,
    unsigned short* __restrict__ m_buf, float* __restrict__ trans_buf)
{
    __shared__ unsigned short e_lds[256 * 130];
    __shared__ float rad_lds[256];
    __shared__ float dif_lds[256 * 3];
    __shared__ float msk_lds[256];
    __shared__ int   ri_lds[256];
    __shared__ int   ci_lds[256];

    const int t = threadIdx.x;
    const int ebase = blockIdx.x * 256;

    // phase 0: indices, coord diff, radial, mask
    {
        const int e = ebase + t;
        const int r = eidx[e];
        const int c = eidx[N_EDGES + e];
        ri_lds[t] = r;
        ci_lds[t] = c;
        const float crx = coord[(size_t)r * 3 + 0];
        const float cry = coord[(size_t)r * 3 + 1];
        const float crz = coord[(size_t)r * 3 + 2];
        const float ccx = coord[(size_t)c * 3 + 0];
        const float ccy = coord[(size_t)c * 3 + 1];
        const float ccz = coord[(size_t)c * 3 + 2];
        const float d0 = crx - ccx, d1 = cry - ccy, d2 = crz - ccz;
        dif_lds[t * 3 + 0] = d0;
        dif_lds[t * 3 + 1] = d1;
        dif_lds[t * 3 + 2] = d2;
        rad_lds[t] = d0 * d0 + d1 * d1 + d2 * d2;
        msk_lds[t] = emask[e];
    }
    __syncthreads();

    // phase 1: stage h[row], h[col] rows as bf16
    unsigned int* e32 = (unsigned int*)e_lds;
    for (int idx = t; idx < 256 * 16; idx += 256) {
        const int le = idx >> 4;
        const int part = idx & 15;
        const int r = ri_lds[le];
        const int c = ci_lds[le];
        const float4 vr = *(const float4*)(h + (size_t)r * 64 + part * 4);
        const float4 vc = *(const float4*)(h + (size_t)c * 64 + part * 4);
        const int b = le * 65 + part * 2;
        e32[b + 0]  = pack_bf2(vr.x, vr.y);
        e32[b + 1]  = pack_bf2(vr.z, vr.w);
        e32[b + 32] = pack_bf2(vc.x, vc.y);
        e32[b + 33] = pack_bf2(vc.z, vc.w);
    }
    __syncthreads();

    // phase 2: per-lane MLP chain (lane = edge)
    const int wave = t >> 6;
    const int lane = t & 63;
    const unsigned short* my_e = e_lds + t * 130;
    float* my_m = ((float*)(e_lds + wave * 64 * 130)) + lane * 65;
    const float radial = rad_lds[t];
    const int e = ebase + t;

    float acc[64];
    // --- edge layer 1 ---
    #pragma unroll
    for (int c = 0; c < 64; c++) acc[c] = fmaf(radial, We1[128 * 64 + c], be1[c]);
    for (int k = 0; k < 128; k++) {
        const float ek = bf16_to_f(my_e[k]);
        const float* __restrict__ w = We1 + k * 64;
        #pragma unroll
        for (int c = 0; c < 64; c++) acc[c] = fmaf(ek, w[c], acc[c]);
    }
    #pragma unroll
    for (int c = 0; c < 64; c++) my_m[c] = fast_silu(acc[c]);

    // --- edge layer 2 ---
    #pragma unroll
    for (int c = 0; c < 64; c++) acc[c] = be2[c];
    for (int k = 0; k < 64; k++) {
        const float mk = my_m[k];
        const float* __restrict__ w = We2 + k * 64;
        #pragma unroll
        for (int c = 0; c < 64; c++) acc[c] = fmaf(mk, w[c], acc[c]);
    }
    const float mask = msk_lds[t];
    #pragma unroll
    for (int c = 0; c < 64; c++) acc[c] = fast_silu(acc[c]) * mask;

    // stash m for coord-mlp; store m (bf16) to global
    #pragma unroll
    for (int c = 0; c < 64; c++) my_m[c] = acc[c];
    {
        uint4* dst = (uint4*)(m_buf + (size_t)e * 64);
        #pragma unroll
        for (int q = 0; q < 8; q++) {
            uint4 v;
            v.x = pack_bf2(acc[8 * q + 0], acc[8 * q + 1]);
            v.y = pack_bf2(acc[8 * q + 2], acc[8 * q + 3]);
            v.z = pack_bf2(acc[8 * q + 4], acc[8 * q + 5]);
            v.w = pack_bf2(acc[8 * q + 6], acc[8 * q + 7]);
            dst[q] = v;
        }
    }

    // --- coord mlp ---
    #pragma unroll
    for (int c = 0; c < 64; c++) acc[c] = bc1[c];
    for (int k = 0; k < 64; k++) {
        const float mk = my_m[k];
        const float* __restrict__ w = Wc1 + k * 64;
        #pragma unroll
        for (int c = 0; c < 64; c++) acc[c] = fmaf(mk, w[c], acc[c]);
    }
    float cval = 0.0f;
    #pragma unroll
    for (int k = 0; k < 64; k++) cval = fmaf(fast_silu(acc[k]), Wc2[k], cval);
    cval *= mask;

    trans_buf[(size_t)e * 3 + 0] = dif_lds[t * 3 + 0] * cval;
    trans_buf[(size_t)e * 3 + 1] = dif_lds[t * 3 + 1] * cval;
    trans_buf[(size_t)e * 3 + 2] = dif_lds[t * 3 + 2] * cval;
}

// --- gather-aggregate: wave per node, lane = channel ---
__global__ __launch_bounds__(256) void agg_kernel(
    const unsigned short* __restrict__ m_buf, const float* __restrict__ trans_buf,
    const int* __restrict__ edge_order, const int* __restrict__ offs,
    const int* __restrict__ hist,
    float* __restrict__ agg, float* __restrict__ aggc)
{
    const int t = threadIdx.x;
    const int node = blockIdx.x * 4 + (t >> 6);
    const int lane = t & 63;
    if (node >= N_NODES) return;
    const int start = offs[node];
    const int deg = hist[node];
    float a = 0.0f, tc = 0.0f;
    for (int i = 0; i < deg; i++) {
        const int e = edge_order[start + i];
        a += bf16_to_f(m_buf[(size_t)e * 64 + lane]);
        if (lane < 3) tc += trans_buf[(size_t)e * 3 + lane];
    }
    agg[(size_t)node * 64 + lane] = a;
    if (lane < 3) aggc[(size_t)node * 3 + lane] = tc;
}

// --- coord output using integer degree ---
__global__ void coord_kernel_csr(const float* __restrict__ coord,
                                 const float* __restrict__ aggc,
                                 const int* __restrict__ hist,
                                 float* __restrict__ cout)
{
    const int i = blockIdx.x * 256 + threadIdx.x;
    if (i < N_NODES * 3) {
        const int node = i / 3;
        const float c = fmaxf((float)hist[node], 1.0f);
        cout[i] = coord[i] + aggc[i] * __builtin_amdgcn_rcpf(c);
    }
}

// ============================================================================
// node kernel (shared by both paths)
// ============================================================================
__global__ __launch_bounds__(256, 2) void egcl_node_kernel(
    const float* __restrict__ h, const float* __restrict__ agg,
    const float* __restrict__ Wn1, const float* __restrict__ bn1,
    const float* __restrict__ Wn2, const float* __restrict__ bn2,
    float* __restrict__ hout)
{
    __shared__ unsigned short n_lds[256 * 130];
    const int t = threadIdx.x;
    const int nbase = blockIdx.x * 256;

    unsigned int* n32 = (unsigned int*)n_lds;
    for (int idx = t; idx < 256 * 16; idx += 256) {
        const int ln = idx >> 4;
        const int part = idx & 15;
        const int node = nbase + ln;
        float4 vh = make_float4(0.f, 0.f, 0.f, 0.f);
        float4 va = make_float4(0.f, 0.f, 0.f, 0.f);
        if (node < N_NODES) {
            vh = *(const float4*)(h + (size_t)node * 64 + part * 4);
            va = *(const float4*)(agg + (size_t)node * 64 + part * 4);
        }
        const int b = ln * 65 + part * 2;
        n32[b + 0]  = pack_bf2(vh.x, vh.y);
        n32[b + 1]  = pack_bf2(vh.z, vh.w);
        n32[b + 32] = pack_bf2(va.x, va.y);
        n32[b + 33] = pack_bf2(va.z, va.w);
    }
    __syncthreads();

    const int node = nbase + t;
    if (node >= N_NODES) return;

    const int wave = t >> 6;
    const int lane = t & 63;
    const unsigned short* my_n = n_lds + t * 130;
    float* my_m = ((float*)(n_lds + wave * 64 * 130)) + lane * 65;

    float acc[64];
    #pragma unroll
    for (int c = 0; c < 64; c++) acc[c] = bn1[c];
    for (int k = 0; k < 128; k++) {
        const float nk = bf16_to_f(my_n[k]);
        const float* __restrict__ w = Wn1 + k * 64;
        #pragma unroll
        for (int c = 0; c < 64; c++) acc[c] = fmaf(nk, w[c], acc[c]);
    }
    #pragma unroll
    for (int c = 0; c < 64; c++) my_m[c] = fast_silu(acc[c]);

    #pragma unroll
    for (int c = 0; c < 64; c++) acc[c] = bn2[c];
    for (int k = 0; k < 64; k++) {
        const float mk = my_m[k];
        const float* __restrict__ w = Wn2 + k * 64;
        #pragma unroll
        for (int c = 0; c < 64; c++) acc[c] = fmaf(mk, w[c], acc[c]);
    }

    float* orow = hout + (size_t)node * 64;
    #pragma unroll
    for (int c = 0; c < 16; c++) {
        float4 v = make_float4(acc[4 * c + 0], acc[4 * c + 1], acc[4 * c + 2], acc[4 * c + 3]);
        *(float4*)(orow + 4 * c) = v;
    }
}

// ============================================================================
// FALLBACK PATH (atomic aggregation, round-1 version) — used if ws too small
// ============================================================================
__global__ __launch_bounds__(256, 2) void egcl_edge_kernel_atomic(
    const float* __restrict__ h, const float* __restrict__ coord,
    const int* __restrict__ eidx, const float* __restrict__ emask,
    const float* __restrict__ We1, const float* __restrict__ be1,
    const float* __restrict__ We2, const float* __restrict__ be2,
    const float* __restrict__ Wc1, const float* __restrict__ bc1,
    const float* __restrict__ Wc2,
    float* __restrict__ agg, float* __restrict__ aggc, float* __restrict__ cnt)
{
    __shared__ unsigned short e_lds[256 * 130];
    __shared__ float rad_lds[256];
    __shared__ float dif_lds[256 * 3];
    __shared__ float msk_lds[256];
    __shared__ int   ri_lds[256];
    __shared__ int   ci_lds[256];

    const int t = threadIdx.x;
    const int ebase = blockIdx.x * 256;
    {
        const int e = ebase + t;
        const int r = eidx[e];
        const int c = eidx[N_EDGES + e];
        ri_lds[t] = r;  ci_lds[t] = c;
        const float d0 = coord[(size_t)r*3+0] - coord[(size_t)c*3+0];
        const float d1 = coord[(size_t)r*3+1] - coord[(size_t)c*3+1];
        const float d2 = coord[(size_t)r*3+2] - coord[(size_t)c*3+2];
        dif_lds[t*3+0] = d0; dif_lds[t*3+1] = d1; dif_lds[t*3+2] = d2;
        rad_lds[t] = d0*d0 + d1*d1 + d2*d2;
        msk_lds[t] = emask[e];
    }
    __syncthreads();
    unsigned int* e32 = (unsigned int*)e_lds;
    for (int idx = t; idx < 256 * 16; idx += 256) {
        const int le = idx >> 4, part = idx & 15;
        const int r = ri_lds[le], c = ci_lds[le];
        const float4 vr = *(const float4*)(h + (size_t)r * 64 + part * 4);
        const float4 vc = *(const float4*)(h + (size_t)c * 64 + part * 4);
        const int b = le * 65 + part * 2;
        e32[b+0] = pack_bf2(vr.x, vr.y); e32[b+1] = pack_bf2(vr.z, vr.w);
        e32[b+32] = pack_bf2(vc.x, vc.y); e32[b+33] = pack_bf2(vc.z, vc.w);
    }
    __syncthreads();
    const int wave = t >> 6, lane = t & 63;
    const unsigned short* my_e = e_lds + t * 130;
    float* my_m = ((float*)(e_lds + wave * 64 * 130)) + lane * 65;
    const float radial = rad_lds[t];
    float acc[64];
    #pragma unroll
    for (int c = 0; c < 64; c++) acc[c] = fmaf(radial, We1[128*64+c], be1[c]);
    for (int k = 0; k < 128; k++) {
        const float ek = bf16_to_f(my_e[k]);
        const float* __restrict__ w = We1 + k * 64;
        #pragma unroll
        for (int c = 0; c < 64; c++) acc[c] = fmaf(ek, w[c], acc[c]);
    }
    #pragma unroll
    for (int c = 0; c < 64; c++) my_m[c] = fast_silu(acc[c]);
    #pragma unroll
    for (int c = 0; c < 64; c++) acc[c] = be2[c];
    for (int k = 0; k < 64; k++) {
        const float mk = my_m[k];
        const float* __restrict__ w = We2 + k * 64;
        #pragma unroll
        for (int c = 0; c < 64; c++) acc[c] = fmaf(mk, w[c], acc[c]);
    }
    const float mask = msk_lds[t];
    #pragma unroll
    for (int c = 0; c < 64; c++) acc[c] = fast_silu(acc[c]) * mask;
    #pragma unroll
    for (int c = 0; c < 64; c++) my_m[c] = acc[c];
    const int r = ri_lds[t];
    float* aggrow = agg + (size_t)r * 64;
    #pragma unroll
    for (int c = 0; c < 64; c++) atomicAdd(aggrow + c, acc[c]);
    #pragma unroll
    for (int c = 0; c < 64; c++) acc[c] = bc1[c];
    for (int k = 0; k < 64; k++) {
        const float mk = my_m[k];
        const float* __restrict__ w = Wc1 + k * 64;
        #pragma unroll
        for (int c = 0; c < 64; c++) acc[c] = fmaf(mk, w[c], acc[c]);
    }
    float cval = 0.0f;
    #pragma unroll
    for (int k = 0; k < 64; k++) cval = fmaf(fast_silu(acc[k]), Wc2[k], cval);
    cval *= mask;
    atomicAdd(aggc + (size_t)r*3+0, dif_lds[t*3+0]*cval);
    atomicAdd(aggc + (size_t)r*3+1, dif_lds[t*3+1]*cval);
    atomicAdd(aggc + (size_t)r*3+2, dif_lds[t*3+2]*cval);
    atomicAdd(cnt + r, 1.0f);
}

__global__ void coord_kernel_atomic(const float* __restrict__ coord,
                                    const float* __restrict__ aggc,
                                    const float* __restrict__ cnt,
                                    float* __restrict__ cout)
{
    const int i = blockIdx.x * 256 + threadIdx.x;
    if (i < N_NODES * 3) {
        const int node = i / 3;
        cout[i] = coord[i] + aggc[i] * __builtin_amdgcn_rcpf(fmaxf(cnt[node], 1.0f));
    }
}

// ============================================================================
// launch
// ============================================================================
extern "C" void kernel_launch(void* const* d_in, const int* in_sizes, int n_in,
                              void* d_out, int out_size, void* d_ws, size_t ws_size,
                              hipStream_t stream)
{
    const float* h     = (const float*)d_in[0];
    const float* coord = (const float*)d_in[1];
    const int*   eidx  = (const int*)d_in[2];
    const float* emask = (const float*)d_in[3];
    const float* We1   = (const float*)d_in[4];
    const float* be1   = (const float*)d_in[5];
    const float* We2   = (const float*)d_in[6];
    const float* be2   = (const float*)d_in[7];
    const float* Wn1   = (const float*)d_in[8];
    const float* bn1   = (const float*)d_in[9];
    const float* Wn2   = (const float*)d_in[10];
    const float* bn2   = (const float*)d_in[11];
    const float* Wc1   = (const float*)d_in[12];
    const float* bc1   = (const float*)d_in[13];
    const float* Wc2   = (const float*)d_in[14];

    float* hout = (float*)d_out;
    float* cout = hout + (size_t)N_NODES * 64;

    // fast-path workspace layout
    char* p = (char*)d_ws;
    int*   hist       = (int*)p;                 p += (size_t)N_NODES * 4;
    int*   offs       = (int*)p;                 p += (size_t)N_NODES * 4;
    int*   pos        = (int*)p;                 p += (size_t)N_NODES * 4;
    int*   edge_order = (int*)p;                 p += (size_t)N_EDGES * 4;
    unsigned short* m_buf = (unsigned short*)p;  p += (size_t)N_EDGES * 64 * 2;
    float* trans_buf  = (float*)p;               p += (size_t)N_EDGES * 3 * 4;
    float* agg        = (float*)p;               p += (size_t)N_NODES * 64 * 4;
    float* aggc       = (float*)p;               p += (size_t)N_NODES * 3 * 4;
    const size_t need = (size_t)(p - (char*)d_ws);

    if (ws_size >= need) {
        // ---- fast path: CSR gather, no fp32 atomics ----
        hipMemsetAsync(hist, 0, (size_t)N_NODES * 4, stream);
        hist_kernel<<<(N_EDGES + 255) / 256, 256, 0, stream>>>(eidx, hist);
        scan_kernel<<<1, 1024, 0, stream>>>(hist, offs, pos);
        scatter_kernel<<<(N_EDGES + 255) / 256, 256, 0, stream>>>(eidx, pos, edge_order);
        egcl_edge_kernel<<<N_EDGES / 256, 256, 0, stream>>>(
            h, coord, eidx, emask, We1, be1, We2, be2, Wc1, bc1, Wc2, m_buf, trans_buf);
        agg_kernel<<<(N_NODES + 3) / 4, 256, 0, stream>>>(
            m_buf, trans_buf, edge_order, offs, hist, agg, aggc);
        egcl_node_kernel<<<(N_NODES + 255) / 256, 256, 0, stream>>>(
            h, agg, Wn1, bn1, Wn2, bn2, hout);
        coord_kernel_csr<<<(N_NODES * 3 + 255) / 256, 256, 0, stream>>>(
            coord, aggc, hist, cout);
    } else {
        // ---- fallback: atomic aggregation ----
        float* f_agg  = (float*)d_ws;
        float* f_aggc = f_agg + (size_t)N_NODES * 64;
        float* f_cnt  = f_aggc + (size_t)N_NODES * 3;
        hipMemsetAsync(d_ws, 0, (size_t)(N_NODES * 64 + N_NODES * 3 + N_NODES) * 4, stream);
        egcl_edge_kernel_atomic<<<N_EDGES / 256, 256, 0, stream>>>(
            h, coord, eidx, emask, We1, be1, We2, be2, Wc1, bc1, Wc2, f_agg, f_aggc, f_cnt);
        egcl_node_kernel<<<(N_NODES + 255) / 256, 256, 0, stream>>>(
            h, f_agg, Wn1, bn1, Wn2, bn2, hout);
        coord_kernel_atomic<<<(N_NODES * 3 + 255) / 256, 256, 0, stream>>>(
            coord, f_aggc, f_cnt, cout);
    }
}

// Round 3
// 607.956 us; speedup vs baseline: 8.0624x; 2.2081x over previous
//
#include <hip/hip_runtime.h>
#include <stdint.h>

#define N_NODES 40000
#define N_EDGES 1280000

typedef __attribute__((ext_vector_type(8))) short bf16x8;   // 8 bf16 in 4 VGPRs
typedef __attribute__((ext_vector_type(4))) float f32x4;    // MFMA C/D

#define MFMA16(a, b, c) __builtin_amdgcn_mfma_f32_16x16x32_bf16((a), (b), (c), 0, 0, 0)

// ---------- helpers ----------
__device__ __forceinline__ float fast_silu(float x) {
    float e = __expf(-x);
    return x * __builtin_amdgcn_rcpf(1.0f + e);
}

__device__ __forceinline__ unsigned short f2bf(float x) {
    unsigned int u = __float_as_uint(x);
    u = (u + 0x7FFFu + ((u >> 16) & 1u)) >> 16;
    return (unsigned short)u;
}

__device__ __forceinline__ unsigned int pack_bf2(float a, float b) {
    unsigned int ua = __float_as_uint(a);
    unsigned int ub = __float_as_uint(b);
    ua = (ua + 0x7FFFu + ((ua >> 16) & 1u)) >> 16;
    ub = (ub + 0x7FFFu + ((ub >> 16) & 1u)) & 0xFFFF0000u;
    return (ua & 0xFFFFu) | ub;
}

__device__ __forceinline__ float bf16_to_f(unsigned short s) {
    return __uint_as_float(((unsigned int)s) << 16);
}

// ============================================================================
// weight prep: transpose + bf16-pack -> Wt[n][k] (contiguous k)
// ============================================================================
__global__ void pack_weights_kernel(const float* __restrict__ We1, const float* __restrict__ We2,
                                    const float* __restrict__ Wc1, const float* __restrict__ Wn1,
                                    const float* __restrict__ Wn2,
                                    unsigned short* __restrict__ Wt1, unsigned short* __restrict__ Wt2,
                                    unsigned short* __restrict__ Wtc1, unsigned short* __restrict__ Wtn1,
                                    unsigned short* __restrict__ Wtn2)
{
    const int t = blockIdx.x * 256 + threadIdx.x;
    if (t < 8192)       { Wt1[t]  = f2bf(We1[(t & 127) * 64 + (t >> 7)]); }
    else if (t < 12288) { int u = t - 8192;  Wt2[u]  = f2bf(We2[(u & 63) * 64 + (u >> 6)]); }
    else if (t < 16384) { int u = t - 12288; Wtc1[u] = f2bf(Wc1[(u & 63) * 64 + (u >> 6)]); }
    else if (t < 24576) { int u = t - 16384; Wtn1[u] = f2bf(Wn1[(u & 127) * 64 + (u >> 7)]); }
    else if (t < 28672) { int u = t - 24576; Wtn2[u] = f2bf(Wn2[(u & 63) * 64 + (u >> 6)]); }
}

// ============================================================================
// CSR prep
// ============================================================================
__global__ void hist_kernel(const int* __restrict__ eidx, int* __restrict__ hist) {
    const int e = blockIdx.x * 256 + threadIdx.x;
    if (e < N_EDGES) atomicAdd(&hist[eidx[e]], 1);
}

__global__ __launch_bounds__(1024) void scan_kernel(const int* __restrict__ hist,
                                                    int* __restrict__ offs,
                                                    int* __restrict__ pos) {
    __shared__ int wtot[16];
    __shared__ int carry_s;
    const int t = threadIdx.x;
    const int wave = t >> 6, lane = t & 63;
    if (t == 0) carry_s = 0;
    __syncthreads();
    for (int base = 0; base < N_NODES; base += 1024) {
        const int idx = base + t;
        int orig = (idx < N_NODES) ? hist[idx] : 0;
        int v = orig;
        #pragma unroll
        for (int d = 1; d < 64; d <<= 1) {
            int u = __shfl_up(v, d, 64);
            if (lane >= d) v += u;
        }
        if (lane == 63) wtot[wave] = v;
        __syncthreads();
        if (wave == 0 && lane < 16) {
            int w = wtot[lane];
            #pragma unroll
            for (int d = 1; d < 16; d <<= 1) {
                int u = __shfl_up(w, d, 64);
                if (lane >= d) w += u;
            }
            wtot[lane] = w;
        }
        __syncthreads();
        const int wbase = (wave == 0) ? 0 : wtot[wave - 1];
        const int c = carry_s;
        const int excl = c + wbase + v - orig;
        if (idx < N_NODES) { offs[idx] = excl; pos[idx] = excl; }
        __syncthreads();
        if (t == 0) carry_s = c + wtot[15];
        __syncthreads();
    }
}

__global__ void scatter_kernel(const int* __restrict__ eidx,
                               int* __restrict__ pos, int* __restrict__ edge_order) {
    const int e = blockIdx.x * 256 + threadIdx.x;
    if (e < N_EDGES) {
        const int r = eidx[e];
        const int slot = atomicAdd(&pos[r], 1);
        edge_order[slot] = e;
    }
}

// ============================================================================
// edge kernel: 3 fused GEMMs on MFMA. Block = 256 edges, 4 waves.
// Wave owns rows [wave*64, wave*64+64) -> 4 row-tiles x 4 col-tiles.
// A tile: [256][72] bf16 (stride 72 shorts = 144 B: 16B-aligned, <=2-way banks).
// ============================================================================
__global__ __launch_bounds__(256, 2) void egcl_edge_mfma(
    const float* __restrict__ h, const float* __restrict__ coord,
    const int* __restrict__ eidx, const float* __restrict__ emask,
    const float* __restrict__ We1, const float* __restrict__ be1,
    const float* __restrict__ be2, const float* __restrict__ bc1,
    const float* __restrict__ Wc2,
    const unsigned short* __restrict__ Wt1, const unsigned short* __restrict__ Wt2,
    const unsigned short* __restrict__ Wtc1,
    unsigned short* __restrict__ m_buf, float* __restrict__ trans_buf)
{
    __shared__ unsigned short A[256 * 72];
    __shared__ float rad_s[256];
    __shared__ float dif_s[768];
    __shared__ float msk_s[256];
    __shared__ float cval_s[256];
    __shared__ int ri_s[256];
    __shared__ int ci_s[256];

    const int t = threadIdx.x;
    const int wave = t >> 6, L = t & 63;
    const int q = L >> 4, lc = L & 15;
    const int ebase = blockIdx.x * 256;
    const int rbase = wave * 64;

    // ---- meta: one edge per thread ----
    {
        const int e = ebase + t;
        const int r = eidx[e];
        const int c = eidx[N_EDGES + e];
        ri_s[t] = r; ci_s[t] = c;
        const float d0 = coord[(size_t)r * 3 + 0] - coord[(size_t)c * 3 + 0];
        const float d1 = coord[(size_t)r * 3 + 1] - coord[(size_t)c * 3 + 1];
        const float d2 = coord[(size_t)r * 3 + 2] - coord[(size_t)c * 3 + 2];
        dif_s[t * 3 + 0] = d0; dif_s[t * 3 + 1] = d1; dif_s[t * 3 + 2] = d2;
        rad_s[t] = d0 * d0 + d1 * d1 + d2 * d2;
        msk_s[t] = emask[e];
    }
    __syncthreads();

    // ---- stage h[row] (k = 0..63) ----
    #pragma unroll 4
    for (int it = 0; it < 16; ++it) {
        const int idx = it * 256 + t;
        const int le = idx >> 4, part = idx & 15;
        const float4 v = *(const float4*)(h + (size_t)ri_s[le] * 64 + part * 4);
        *(uint2*)&A[le * 72 + part * 4] = make_uint2(pack_bf2(v.x, v.y), pack_bf2(v.z, v.w));
    }

    // ---- layer1 init: be1[col] + radial[row] * We1[128][col] ----
    f32x4 acc1[4][4];
    #pragma unroll
    for (int ct = 0; ct < 4; ++ct) {
        const float b = be1[ct * 16 + lc];
        const float w = We1[128 * 64 + ct * 16 + lc];
        #pragma unroll
        for (int rt = 0; rt < 4; ++rt) {
            #pragma unroll
            for (int i = 0; i < 4; ++i)
                acc1[rt][ct][i] = fmaf(rad_s[rbase + rt * 16 + q * 4 + i], w, b);
        }
    }
    __syncthreads();

    // ---- layer1 MFMA, k = 0..63 (h[row]) ----
    #pragma unroll
    for (int ks = 0; ks < 2; ++ks) {
        bf16x8 af[4];
        #pragma unroll
        for (int rt = 0; rt < 4; ++rt)
            af[rt] = *(const bf16x8*)&A[(rbase + rt * 16 + lc) * 72 + ks * 32 + q * 8];
        #pragma unroll
        for (int ct = 0; ct < 4; ++ct) {
            const bf16x8 bf = *(const bf16x8*)&Wt1[(ct * 16 + lc) * 128 + ks * 32 + q * 8];
            #pragma unroll
            for (int rt = 0; rt < 4; ++rt)
                acc1[rt][ct] = MFMA16(af[rt], bf, acc1[rt][ct]);
        }
    }
    __syncthreads();

    // ---- stage h[col] over A ----
    #pragma unroll 4
    for (int it = 0; it < 16; ++it) {
        const int idx = it * 256 + t;
        const int le = idx >> 4, part = idx & 15;
        const float4 v = *(const float4*)(h + (size_t)ci_s[le] * 64 + part * 4);
        *(uint2*)&A[le * 72 + part * 4] = make_uint2(pack_bf2(v.x, v.y), pack_bf2(v.z, v.w));
    }
    __syncthreads();

    // ---- layer1 MFMA, k = 64..127 (h[col]) ----
    #pragma unroll
    for (int ks = 0; ks < 2; ++ks) {
        bf16x8 af[4];
        #pragma unroll
        for (int rt = 0; rt < 4; ++rt)
            af[rt] = *(const bf16x8*)&A[(rbase + rt * 16 + lc) * 72 + ks * 32 + q * 8];
        #pragma unroll
        for (int ct = 0; ct < 4; ++ct) {
            const bf16x8 bf = *(const bf16x8*)&Wt1[(ct * 16 + lc) * 128 + 64 + ks * 32 + q * 8];
            #pragma unroll
            for (int rt = 0; rt < 4; ++rt)
                acc1[rt][ct] = MFMA16(af[rt], bf, acc1[rt][ct]);
        }
    }
    __syncthreads();   // all waves done reading A

    // ---- m1 = silu(C1) -> A (C/D layout -> A layout via LDS) ----
    #pragma unroll
    for (int rt = 0; rt < 4; ++rt)
        #pragma unroll
        for (int ct = 0; ct < 4; ++ct)
            #pragma unroll
            for (int i = 0; i < 4; ++i) {
                const int row = rbase + rt * 16 + q * 4 + i;
                A[row * 72 + ct * 16 + lc] = f2bf(fast_silu(acc1[rt][ct][i]));
            }
    __syncthreads();

    // ---- layer2 ----
    f32x4 acc2[4][4];
    #pragma unroll
    for (int ct = 0; ct < 4; ++ct) {
        const float b = be2[ct * 16 + lc];
        #pragma unroll
        for (int rt = 0; rt < 4; ++rt)
            #pragma unroll
            for (int i = 0; i < 4; ++i) acc2[rt][ct][i] = b;
    }
    #pragma unroll
    for (int ks = 0; ks < 2; ++ks) {
        bf16x8 af[4];
        #pragma unroll
        for (int rt = 0; rt < 4; ++rt)
            af[rt] = *(const bf16x8*)&A[(rbase + rt * 16 + lc) * 72 + ks * 32 + q * 8];
        #pragma unroll
        for (int ct = 0; ct < 4; ++ct) {
            const bf16x8 bf = *(const bf16x8*)&Wt2[(ct * 16 + lc) * 64 + ks * 32 + q * 8];
            #pragma unroll
            for (int rt = 0; rt < 4; ++rt)
                acc2[rt][ct] = MFMA16(af[rt], bf, acc2[rt][ct]);
        }
    }
    __syncthreads();   // all waves done reading m1 from A

    // ---- m = silu(C2) * mask -> A ----
    #pragma unroll
    for (int rt = 0; rt < 4; ++rt)
        #pragma unroll
        for (int ct = 0; ct < 4; ++ct)
            #pragma unroll
            for (int i = 0; i < 4; ++i) {
                const int row = rbase + rt * 16 + q * 4 + i;
                const float v = fast_silu(acc2[rt][ct][i]) * msk_s[row];
                A[row * 72 + ct * 16 + lc] = f2bf(v);
            }
    __syncthreads();

    // ---- export m to global (coalesced 16B/lane) ----
    #pragma unroll
    for (int it = 0; it < 8; ++it) {
        const int idx = it * 256 + t;
        const int le = idx >> 3, part = idx & 7;
        const bf16x8 v = *(const bf16x8*)&A[le * 72 + part * 8];
        *(bf16x8*)(m_buf + (size_t)(ebase + le) * 64 + part * 8) = v;
    }

    // ---- coord mlp: silu(m@Wc1+bc1)@Wc2 ----
    f32x4 acc3[4][4];
    #pragma unroll
    for (int ct = 0; ct < 4; ++ct) {
        const float b = bc1[ct * 16 + lc];
        #pragma unroll
        for (int rt = 0; rt < 4; ++rt)
            #pragma unroll
            for (int i = 0; i < 4; ++i) acc3[rt][ct][i] = b;
    }
    #pragma unroll
    for (int ks = 0; ks < 2; ++ks) {
        bf16x8 af[4];
        #pragma unroll
        for (int rt = 0; rt < 4; ++rt)
            af[rt] = *(const bf16x8*)&A[(rbase + rt * 16 + lc) * 72 + ks * 32 + q * 8];
        #pragma unroll
        for (int ct = 0; ct < 4; ++ct) {
            const bf16x8 bf = *(const bf16x8*)&Wtc1[(ct * 16 + lc) * 64 + ks * 32 + q * 8];
            #pragma unroll
            for (int rt = 0; rt < 4; ++rt)
                acc3[rt][ct] = MFMA16(af[rt], bf, acc3[rt][ct]);
        }
    }
    // final dot with Wc2[64]: reduce across col groups
    {
        float wc2v[4];
        #pragma unroll
        for (int ct = 0; ct < 4; ++ct) wc2v[ct] = Wc2[ct * 16 + lc];
        #pragma unroll
        for (int rt = 0; rt < 4; ++rt)
            #pragma unroll
            for (int i = 0; i < 4; ++i) {
                float s = 0.0f;
                #pragma unroll
                for (int ct = 0; ct < 4; ++ct)
                    s = fmaf(fast_silu(acc3[rt][ct][i]), wc2v[ct], s);
                s += __shfl_xor(s, 1, 16);
                s += __shfl_xor(s, 2, 16);
                s += __shfl_xor(s, 4, 16);
                s += __shfl_xor(s, 8, 16);
                if (lc == 0) cval_s[rbase + rt * 16 + q * 4 + i] = s;
            }
    }
    __syncthreads();

    // ---- trans = coord_diff * c * mask ----
    {
        const float c = cval_s[t] * msk_s[t];
        const size_t e = ebase + t;
        trans_buf[e * 3 + 0] = dif_s[t * 3 + 0] * c;
        trans_buf[e * 3 + 1] = dif_s[t * 3 + 1] * c;
        trans_buf[e * 3 + 2] = dif_s[t * 3 + 2] * c;
    }
}

// ============================================================================
// gather-aggregate: wave per node, lane = channel
// ============================================================================
__global__ __launch_bounds__(256) void agg_kernel(
    const unsigned short* __restrict__ m_buf, const float* __restrict__ trans_buf,
    const int* __restrict__ edge_order, const int* __restrict__ offs,
    const int* __restrict__ hist,
    float* __restrict__ agg, float* __restrict__ aggc)
{
    const int t = threadIdx.x;
    const int node = blockIdx.x * 4 + (t >> 6);
    const int lane = t & 63;
    if (node >= N_NODES) return;
    const int start = offs[node];
    const int deg = hist[node];
    float a = 0.0f, tc = 0.0f;
    for (int i = 0; i < deg; i++) {
        const int e = edge_order[start + i];
        a += bf16_to_f(m_buf[(size_t)e * 64 + lane]);
        if (lane < 3) tc += trans_buf[(size_t)e * 3 + lane];
    }
    agg[(size_t)node * 64 + lane] = a;
    if (lane < 3) aggc[(size_t)node * 3 + lane] = tc;
}

// ============================================================================
// node kernel on MFMA: 128 nodes / block, wave owns 32 rows (2 row-tiles).
// A: [128][136] bf16 for K=128 (h || agg); reused as m[128][72] after layer 1.
// ============================================================================
__global__ __launch_bounds__(256, 2) void egcl_node_mfma(
    const float* __restrict__ h, const float* __restrict__ agg,
    const float* __restrict__ bn1, const float* __restrict__ bn2,
    const unsigned short* __restrict__ Wtn1, const unsigned short* __restrict__ Wtn2,
    float* __restrict__ hout)
{
    __shared__ unsigned short A[128 * 136];
    const int t = threadIdx.x;
    const int wave = t >> 6, L = t & 63;
    const int q = L >> 4, lc = L & 15;
    const int nbase = blockIdx.x * 128;
    const int rbase = wave * 32;

    // stage h (k 0..63) + agg (k 64..127)
    #pragma unroll 4
    for (int it = 0; it < 16; ++it) {
        const int idx = it * 256 + t;
        const int ln = idx >> 5, part = idx & 31;
        const int node = nbase + ln;
        float4 v = make_float4(0.f, 0.f, 0.f, 0.f);
        if (node < N_NODES) {
            v = (part < 16) ? *(const float4*)(h + (size_t)node * 64 + part * 4)
                            : *(const float4*)(agg + (size_t)node * 64 + (part - 16) * 4);
        }
        *(uint2*)&A[ln * 136 + part * 4] = make_uint2(pack_bf2(v.x, v.y), pack_bf2(v.z, v.w));
    }
    __syncthreads();

    f32x4 acc1[2][4];
    #pragma unroll
    for (int ct = 0; ct < 4; ++ct) {
        const float b = bn1[ct * 16 + lc];
        #pragma unroll
        for (int rt = 0; rt < 2; ++rt)
            #pragma unroll
            for (int i = 0; i < 4; ++i) acc1[rt][ct][i] = b;
    }
    #pragma unroll
    for (int ks = 0; ks < 4; ++ks) {
        bf16x8 af[2];
        #pragma unroll
        for (int rt = 0; rt < 2; ++rt)
            af[rt] = *(const bf16x8*)&A[(rbase + rt * 16 + lc) * 136 + ks * 32 + q * 8];
        #pragma unroll
        for (int ct = 0; ct < 4; ++ct) {
            const bf16x8 bf = *(const bf16x8*)&Wtn1[(ct * 16 + lc) * 128 + ks * 32 + q * 8];
            #pragma unroll
            for (int rt = 0; rt < 2; ++rt)
                acc1[rt][ct] = MFMA16(af[rt], bf, acc1[rt][ct]);
        }
    }
    __syncthreads();

    // m = silu -> A (stride 72)
    #pragma unroll
    for (int rt = 0; rt < 2; ++rt)
        #pragma unroll
        for (int ct = 0; ct < 4; ++ct)
            #pragma unroll
            for (int i = 0; i < 4; ++i) {
                const int row = rbase + rt * 16 + q * 4 + i;
                A[row * 72 + ct * 16 + lc] = f2bf(fast_silu(acc1[rt][ct][i]));
            }
    __syncthreads();

    f32x4 acc2[2][4];
    #pragma unroll
    for (int ct = 0; ct < 4; ++ct) {
        const float b = bn2[ct * 16 + lc];
        #pragma unroll
        for (int rt = 0; rt < 2; ++rt)
            #pragma unroll
            for (int i = 0; i < 4; ++i) acc2[rt][ct][i] = b;
    }
    #pragma unroll
    for (int ks = 0; ks < 2; ++ks) {
        bf16x8 af[2];
        #pragma unroll
        for (int rt = 0; rt < 2; ++rt)
            af[rt] = *(const bf16x8*)&A[(rbase + rt * 16 + lc) * 72 + ks * 32 + q * 8];
        #pragma unroll
        for (int ct = 0; ct < 4; ++ct) {
            const bf16x8 bf = *(const bf16x8*)&Wtn2[(ct * 16 + lc) * 64 + ks * 32 + q * 8];
            #pragma unroll
            for (int rt = 0; rt < 2; ++rt)
                acc2[rt][ct] = MFMA16(af[rt], bf, acc2[rt][ct]);
        }
    }

    #pragma unroll
    for (int rt = 0; rt < 2; ++rt)
        #pragma unroll
        for (int ct = 0; ct < 4; ++ct)
            #pragma unroll
            for (int i = 0; i < 4; ++i) {
                const int node = nbase + rbase + rt * 16 + q * 4 + i;
                if (node < N_NODES)
                    hout[(size_t)node * 64 + ct * 16 + lc] = acc2[rt][ct][i];
            }
}

// ============================================================================
// coord output
// ============================================================================
__global__ void coord_kernel_csr(const float* __restrict__ coord,
                                 const float* __restrict__ aggc,
                                 const int* __restrict__ hist,
                                 float* __restrict__ cout)
{
    const int i = blockIdx.x * 256 + threadIdx.x;
    if (i < N_NODES * 3) {
        const int node = i / 3;
        const float c = fmaxf((float)hist[node], 1.0f);
        cout[i] = coord[i] + aggc[i] * __builtin_amdgcn_rcpf(c);
    }
}

// ============================================================================
// launch
// ============================================================================
extern "C" void kernel_launch(void* const* d_in, const int* in_sizes, int n_in,
                              void* d_out, int out_size, void* d_ws, size_t ws_size,
                              hipStream_t stream)
{
    const float* h     = (const float*)d_in[0];
    const float* coord = (const float*)d_in[1];
    const int*   eidx  = (const int*)d_in[2];
    const float* emask = (const float*)d_in[3];
    const float* We1   = (const float*)d_in[4];
    const float* be1   = (const float*)d_in[5];
    const float* We2   = (const float*)d_in[6];
    const float* be2   = (const float*)d_in[7];
    const float* Wn1   = (const float*)d_in[8];
    const float* bn1   = (const float*)d_in[9];
    const float* Wn2   = (const float*)d_in[10];
    const float* bn2   = (const float*)d_in[11];
    const float* Wc1   = (const float*)d_in[12];
    const float* bc1   = (const float*)d_in[13];
    const float* Wc2   = (const float*)d_in[14];

    float* hout = (float*)d_out;
    float* cout = hout + (size_t)N_NODES * 64;

    char* p = (char*)d_ws;
    int*   hist       = (int*)p;                 p += (size_t)N_NODES * 4;
    int*   offs       = (int*)p;                 p += (size_t)N_NODES * 4;
    int*   pos        = (int*)p;                 p += (size_t)N_NODES * 4;
    int*   edge_order = (int*)p;                 p += (size_t)N_EDGES * 4;
    unsigned short* m_buf = (unsigned short*)p;  p += (size_t)N_EDGES * 64 * 2;
    float* trans_buf  = (float*)p;               p += (size_t)N_EDGES * 3 * 4;
    float* agg        = (float*)p;               p += (size_t)N_NODES * 64 * 4;
    float* aggc       = (float*)p;               p += (size_t)N_NODES * 3 * 4;
    unsigned short* Wt1  = (unsigned short*)p;   p += 8192 * 2;
    unsigned short* Wt2  = (unsigned short*)p;   p += 4096 * 2;
    unsigned short* Wtc1 = (unsigned short*)p;   p += 4096 * 2;
    unsigned short* Wtn1 = (unsigned short*)p;   p += 8192 * 2;
    unsigned short* Wtn2 = (unsigned short*)p;   p += 4096 * 2;

    hipMemsetAsync(hist, 0, (size_t)N_NODES * 4, stream);
    pack_weights_kernel<<<112, 256, 0, stream>>>(We1, We2, Wc1, Wn1, Wn2,
                                                 Wt1, Wt2, Wtc1, Wtn1, Wtn2);
    hist_kernel<<<(N_EDGES + 255) / 256, 256, 0, stream>>>(eidx, hist);
    scan_kernel<<<1, 1024, 0, stream>>>(hist, offs, pos);
    scatter_kernel<<<(N_EDGES + 255) / 256, 256, 0, stream>>>(eidx, pos, edge_order);
    egcl_edge_mfma<<<N_EDGES / 256, 256, 0, stream>>>(
        h, coord, eidx, emask, We1, be1, be2, bc1, Wc2, Wt1, Wt2, Wtc1, m_buf, trans_buf);
    agg_kernel<<<(N_NODES + 3) / 4, 256, 0, stream>>>(
        m_buf, trans_buf, edge_order, offs, hist, agg, aggc);
    egcl_node_mfma<<<(N_NODES + 127) / 128, 256, 0, stream>>>(
        h, agg, bn1, bn2, Wtn1, Wtn2, hout);
    coord_kernel_csr<<<(N_NODES * 3 + 255) / 256, 256, 0, stream>>>(
        coord, aggc, hist, cout);
}

// Round 4
// 465.821 us; speedup vs baseline: 10.5224x; 1.3051x over previous
//
#include <hip/hip_runtime.h>
#include <stdint.h>

#define N_NODES 40000
#define N_EDGES 1280000

typedef __attribute__((ext_vector_type(8))) short bf16x8;   // 8 bf16 in 4 VGPRs
typedef __attribute__((ext_vector_type(4))) float f32x4;    // MFMA C/D

#define MFMA16(a, b, c) __builtin_amdgcn_mfma_f32_16x16x32_bf16((a), (b), (c), 0, 0, 0)

// ---------- helpers ----------
__device__ __forceinline__ float fast_silu(float x) {
    float e = __expf(-x);
    return x * __builtin_amdgcn_rcpf(1.0f + e);
}

__device__ __forceinline__ unsigned short f2bf(float x) {
    unsigned int u = __float_as_uint(x);
    u = (u + 0x7FFFu + ((u >> 16) & 1u)) >> 16;
    return (unsigned short)u;
}

__device__ __forceinline__ unsigned int pack_bf2(float a, float b) {
    unsigned int ua = __float_as_uint(a);
    unsigned int ub = __float_as_uint(b);
    ua = (ua + 0x7FFFu + ((ua >> 16) & 1u)) >> 16;
    ub = (ub + 0x7FFFu + ((ub >> 16) & 1u)) & 0xFFFF0000u;
    return (ua & 0xFFFFu) | ub;
}

__device__ __forceinline__ float bf16_to_f(unsigned short s) {
    return __uint_as_float(((unsigned int)s) << 16);
}

// ============================================================================
// prep: pack h -> bf16 and transpose+pack weights (Wt[n][k], contiguous k)
// ============================================================================
__global__ void prep_kernel(const float* __restrict__ h,
                            const float* __restrict__ We1, const float* __restrict__ We2,
                            const float* __restrict__ Wc1, const float* __restrict__ Wn1,
                            const float* __restrict__ Wn2,
                            unsigned short* __restrict__ h_bf,
                            unsigned short* __restrict__ Wt1, unsigned short* __restrict__ Wt2,
                            unsigned short* __restrict__ Wtc1, unsigned short* __restrict__ Wtn1,
                            unsigned short* __restrict__ Wtn2)
{
    const int b = blockIdx.x;
    if (b < 2500) {
        const int i = (b * 256 + threadIdx.x) * 4;   // exactly covers 2,560,000
        const float4 v = *(const float4*)(h + i);
        *(uint2*)(h_bf + i) = make_uint2(pack_bf2(v.x, v.y), pack_bf2(v.z, v.w));
    } else {
        const int t = (b - 2500) * 256 + threadIdx.x;
        if (t < 8192)       { Wt1[t]  = f2bf(We1[(t & 127) * 64 + (t >> 7)]); }
        else if (t < 12288) { int u = t - 8192;  Wt2[u]  = f2bf(We2[(u & 63) * 64 + (u >> 6)]); }
        else if (t < 16384) { int u = t - 12288; Wtc1[u] = f2bf(Wc1[(u & 63) * 64 + (u >> 6)]); }
        else if (t < 24576) { int u = t - 16384; Wtn1[u] = f2bf(Wn1[(u & 127) * 64 + (u >> 7)]); }
        else if (t < 28672) { int u = t - 24576; Wtn2[u] = f2bf(Wn2[(u & 63) * 64 + (u >> 6)]); }
    }
}

// ============================================================================
// CSR prep
// ============================================================================
__global__ void hist_kernel(const int* __restrict__ eidx, int* __restrict__ hist) {
    const int i = (blockIdx.x * 256 + threadIdx.x) * 4;   // 1250 blocks, exact
    const int4 r = *(const int4*)(eidx + i);
    atomicAdd(&hist[r.x], 1);
    atomicAdd(&hist[r.y], 1);
    atomicAdd(&hist[r.z], 1);
    atomicAdd(&hist[r.w], 1);
}

__global__ __launch_bounds__(1024) void scan_kernel(const int* __restrict__ hist,
                                                    int* __restrict__ offs,
                                                    int* __restrict__ pos) {
    __shared__ int wtot[16];
    __shared__ int carry_s;
    const int t = threadIdx.x;
    const int wave = t >> 6, lane = t & 63;
    if (t == 0) carry_s = 0;
    __syncthreads();
    for (int base = 0; base < N_NODES; base += 8192) {
        const int idx = base + t * 8;
        int v[8];
        if (idx + 8 <= N_NODES) {
            const int4 a = *(const int4*)(hist + idx);
            const int4 b = *(const int4*)(hist + idx + 4);
            v[0] = a.x; v[1] = a.y; v[2] = a.z; v[3] = a.w;
            v[4] = b.x; v[5] = b.y; v[6] = b.z; v[7] = b.w;
        } else {
            #pragma unroll
            for (int j = 0; j < 8; ++j) v[j] = (idx + j < N_NODES) ? hist[idx + j] : 0;
        }
        int s = 0;
        #pragma unroll
        for (int j = 0; j < 8; ++j) s += v[j];
        int S = s;
        #pragma unroll
        for (int d = 1; d < 64; d <<= 1) {
            const int u = __shfl_up(S, d, 64);
            if (lane >= d) S += u;
        }
        if (lane == 63) wtot[wave] = S;
        __syncthreads();
        if (wave == 0 && lane < 16) {
            int w = wtot[lane];
            #pragma unroll
            for (int d = 1; d < 16; d <<= 1) {
                const int u = __shfl_up(w, d, 64);
                if (lane >= d) w += u;
            }
            wtot[lane] = w;
        }
        __syncthreads();
        const int wb = (wave == 0) ? 0 : wtot[wave - 1];
        int run = carry_s + wb + (S - s);
        #pragma unroll
        for (int j = 0; j < 8; ++j) {
            if (idx + j < N_NODES) { offs[idx + j] = run; pos[idx + j] = run; }
            run += v[j];
        }
        __syncthreads();
        if (t == 0) carry_s += wtot[15];
        __syncthreads();
    }
}

__global__ void scatter_kernel(const int* __restrict__ eidx,
                               int* __restrict__ pos, int* __restrict__ edge_order) {
    const int i = (blockIdx.x * 256 + threadIdx.x) * 4;
    const int4 r = *(const int4*)(eidx + i);
    const int s0 = atomicAdd(&pos[r.x], 1); edge_order[s0] = i + 0;
    const int s1 = atomicAdd(&pos[r.y], 1); edge_order[s1] = i + 1;
    const int s2 = atomicAdd(&pos[r.z], 1); edge_order[s2] = i + 2;
    const int s3 = atomicAdd(&pos[r.w], 1); edge_order[s3] = i + 3;
}

// ============================================================================
// edge kernel: CSR-ordered, transposed-MFMA, barrier-free (all LDS wave-private)
// Block = 256 slots, 4 waves; wave owns 64 consecutive CSR slots.
// A tile [256][72] bf16; computes C^T = W^T @ X^T so lanes hold 4 consecutive
// out-channels -> packed b64 epilogue writes in row-major m layout.
// ============================================================================
__global__ __launch_bounds__(256, 3) void egcl_edge_mfma(
    const unsigned short* __restrict__ h_bf, const float* __restrict__ coord,
    const int* __restrict__ eidx, const float* __restrict__ emask,
    const int* __restrict__ edge_order,
    const float* __restrict__ We1, const float* __restrict__ be1,
    const float* __restrict__ be2, const float* __restrict__ bc1,
    const float* __restrict__ Wc2,
    const unsigned short* __restrict__ Wt1, const unsigned short* __restrict__ Wt2,
    const unsigned short* __restrict__ Wtc1,
    unsigned short* __restrict__ m_buf, float* __restrict__ trans_buf)
{
    __shared__ __align__(16) unsigned short A[256 * 72];
    __shared__ float rad_s[256];
    __shared__ float dif_s[768];
    __shared__ float msk_s[256];
    __shared__ float cval_s[256];
    __shared__ int ri_s[256];
    __shared__ int ci_s[256];

    const int t = threadIdx.x;
    const int w = t >> 6, L = t & 63;
    const int q = L >> 4, lc = L & 15;
    const int ebase = blockIdx.x * 256;
    const int rbase = w * 64;

    // ---- meta: one CSR slot per thread (slot t is in this thread's own wave) ----
    {
        const int e = edge_order[ebase + t];
        const int r = eidx[e];
        const int c = eidx[N_EDGES + e];
        ri_s[t] = r; ci_s[t] = c;
        const float d0 = coord[r * 3 + 0] - coord[c * 3 + 0];
        const float d1 = coord[r * 3 + 1] - coord[c * 3 + 1];
        const float d2 = coord[r * 3 + 2] - coord[c * 3 + 2];
        dif_s[t * 3 + 0] = d0; dif_s[t * 3 + 1] = d1; dif_s[t * 3 + 2] = d2;
        rad_s[t] = d0 * d0 + d1 * d1 + d2 * d2;
        msk_s[t] = emask[e];
    }

    // ---- stage h_bf[row] (k = 0..63), wave-private rows ----
    #pragma unroll
    for (int it = 0; it < 8; ++it) {
        const int j = it * 64 + L;
        const int row = rbase + (j >> 3);
        const int part = j & 7;
        const bf16x8 v = *(const bf16x8*)(h_bf + (size_t)ri_s[row] * 64 + part * 8);
        *(bf16x8*)&A[row * 72 + part * 8] = v;
    }

    // ---- layer1 init: C^T[out][edge] = be1[out] + radial[edge]*We1[128][out] ----
    f32x4 acc[4][4];   // [ot][et]
    #pragma unroll
    for (int ot = 0; ot < 4; ++ot) {
        const float4 bv = *(const float4*)(be1 + ot * 16 + q * 4);
        const float4 wv = *(const float4*)(We1 + 128 * 64 + ot * 16 + q * 4);
        #pragma unroll
        for (int et = 0; et < 4; ++et) {
            const float rad = rad_s[rbase + et * 16 + lc];
            acc[ot][et][0] = fmaf(rad, wv.x, bv.x);
            acc[ot][et][1] = fmaf(rad, wv.y, bv.y);
            acc[ot][et][2] = fmaf(rad, wv.z, bv.z);
            acc[ot][et][3] = fmaf(rad, wv.w, bv.w);
        }
    }

    // ---- layer1 MFMA, k = 0..63 (h[row]) ----
    #pragma unroll
    for (int ks = 0; ks < 2; ++ks) {
        bf16x8 bfr[4];
        #pragma unroll
        for (int et = 0; et < 4; ++et)
            bfr[et] = *(const bf16x8*)&A[(rbase + et * 16 + lc) * 72 + ks * 32 + q * 8];
        #pragma unroll
        for (int ot = 0; ot < 4; ++ot) {
            const bf16x8 af = *(const bf16x8*)&Wt1[(ot * 16 + lc) * 128 + ks * 32 + q * 8];
            #pragma unroll
            for (int et = 0; et < 4; ++et)
                acc[ot][et] = MFMA16(af, bfr[et], acc[ot][et]);
        }
    }

    // ---- restage h_bf[col] over A (own rows only) ----
    #pragma unroll
    for (int it = 0; it < 8; ++it) {
        const int j = it * 64 + L;
        const int row = rbase + (j >> 3);
        const int part = j & 7;
        const bf16x8 v = *(const bf16x8*)(h_bf + (size_t)ci_s[row] * 64 + part * 8);
        *(bf16x8*)&A[row * 72 + part * 8] = v;
    }

    // ---- layer1 MFMA, k = 64..127 (h[col]) ----
    #pragma unroll
    for (int ks = 0; ks < 2; ++ks) {
        bf16x8 bfr[4];
        #pragma unroll
        for (int et = 0; et < 4; ++et)
            bfr[et] = *(const bf16x8*)&A[(rbase + et * 16 + lc) * 72 + ks * 32 + q * 8];
        #pragma unroll
        for (int ot = 0; ot < 4; ++ot) {
            const bf16x8 af = *(const bf16x8*)&Wt1[(ot * 16 + lc) * 128 + 64 + ks * 32 + q * 8];
            #pragma unroll
            for (int et = 0; et < 4; ++et)
                acc[ot][et] = MFMA16(af, bfr[et], acc[ot][et]);
        }
    }

    // ---- m1 = silu -> A row-major (packed b64 writes, 4 consecutive channels) ----
    #pragma unroll
    for (int et = 0; et < 4; ++et) {
        const int row = rbase + et * 16 + lc;
        #pragma unroll
        for (int ot = 0; ot < 4; ++ot) {
            uint2 p;
            p.x = pack_bf2(fast_silu(acc[ot][et][0]), fast_silu(acc[ot][et][1]));
            p.y = pack_bf2(fast_silu(acc[ot][et][2]), fast_silu(acc[ot][et][3]));
            *(uint2*)&A[row * 72 + ot * 16 + q * 4] = p;
        }
    }

    // ---- layer2 ----
    f32x4 acc2[4][4];
    #pragma unroll
    for (int ot = 0; ot < 4; ++ot) {
        const float4 bv = *(const float4*)(be2 + ot * 16 + q * 4);
        #pragma unroll
        for (int et = 0; et < 4; ++et) {
            acc2[ot][et][0] = bv.x; acc2[ot][et][1] = bv.y;
            acc2[ot][et][2] = bv.z; acc2[ot][et][3] = bv.w;
        }
    }
    #pragma unroll
    for (int ks = 0; ks < 2; ++ks) {
        bf16x8 bfr[4];
        #pragma unroll
        for (int et = 0; et < 4; ++et)
            bfr[et] = *(const bf16x8*)&A[(rbase + et * 16 + lc) * 72 + ks * 32 + q * 8];
        #pragma unroll
        for (int ot = 0; ot < 4; ++ot) {
            const bf16x8 af = *(const bf16x8*)&Wt2[(ot * 16 + lc) * 64 + ks * 32 + q * 8];
            #pragma unroll
            for (int et = 0; et < 4; ++et)
                acc2[ot][et] = MFMA16(af, bfr[et], acc2[ot][et]);
        }
    }

    // ---- m = silu * mask -> A ----
    #pragma unroll
    for (int et = 0; et < 4; ++et) {
        const int row = rbase + et * 16 + lc;
        const float mk = msk_s[row];
        #pragma unroll
        for (int ot = 0; ot < 4; ++ot) {
            uint2 p;
            p.x = pack_bf2(fast_silu(acc2[ot][et][0]) * mk, fast_silu(acc2[ot][et][1]) * mk);
            p.y = pack_bf2(fast_silu(acc2[ot][et][2]) * mk, fast_silu(acc2[ot][et][3]) * mk);
            *(uint2*)&A[row * 72 + ot * 16 + q * 4] = p;
        }
    }

    // ---- export m to global in CSR order (coalesced, wave-private rows) ----
    #pragma unroll
    for (int it = 0; it < 8; ++it) {
        const int j = it * 64 + L;
        const int row = rbase + (j >> 3);
        const int part = j & 7;
        const bf16x8 v = *(const bf16x8*)&A[row * 72 + part * 8];
        *(bf16x8*)(m_buf + (size_t)(ebase + row) * 64 + part * 8) = v;
    }

    // ---- coord mlp ----
    f32x4 acc3[4][4];
    #pragma unroll
    for (int ot = 0; ot < 4; ++ot) {
        const float4 bv = *(const float4*)(bc1 + ot * 16 + q * 4);
        #pragma unroll
        for (int et = 0; et < 4; ++et) {
            acc3[ot][et][0] = bv.x; acc3[ot][et][1] = bv.y;
            acc3[ot][et][2] = bv.z; acc3[ot][et][3] = bv.w;
        }
    }
    #pragma unroll
    for (int ks = 0; ks < 2; ++ks) {
        bf16x8 bfr[4];
        #pragma unroll
        for (int et = 0; et < 4; ++et)
            bfr[et] = *(const bf16x8*)&A[(rbase + et * 16 + lc) * 72 + ks * 32 + q * 8];
        #pragma unroll
        for (int ot = 0; ot < 4; ++ot) {
            const bf16x8 af = *(const bf16x8*)&Wtc1[(ot * 16 + lc) * 64 + ks * 32 + q * 8];
            #pragma unroll
            for (int et = 0; et < 4; ++et)
                acc3[ot][et] = MFMA16(af, bfr[et], acc3[ot][et]);
        }
    }
    // final dot with Wc2: sum over out-channels, reduce across q groups
    {
        float4 wv[4];
        #pragma unroll
        for (int ot = 0; ot < 4; ++ot) wv[ot] = *(const float4*)(Wc2 + ot * 16 + q * 4);
        #pragma unroll
        for (int et = 0; et < 4; ++et) {
            float s = 0.0f;
            #pragma unroll
            for (int ot = 0; ot < 4; ++ot) {
                s = fmaf(fast_silu(acc3[ot][et][0]), wv[ot].x, s);
                s = fmaf(fast_silu(acc3[ot][et][1]), wv[ot].y, s);
                s = fmaf(fast_silu(acc3[ot][et][2]), wv[ot].z, s);
                s = fmaf(fast_silu(acc3[ot][et][3]), wv[ot].w, s);
            }
            s += __shfl_xor(s, 16, 64);
            s += __shfl_xor(s, 32, 64);
            if (q == 0) cval_s[rbase + et * 16 + lc] = s;
        }
    }

    // ---- trans = coord_diff * c * mask (CSR order) ----
    {
        const float cv = cval_s[t] * msk_s[t];
        const size_t s = ebase + t;
        trans_buf[s * 3 + 0] = dif_s[t * 3 + 0] * cv;
        trans_buf[s * 3 + 1] = dif_s[t * 3 + 1] * cv;
        trans_buf[s * 3 + 2] = dif_s[t * 3 + 2] * cv;
    }
}

// ============================================================================
// streaming aggregate: wave per node, contiguous CSR range, no atomics
// ============================================================================
__global__ __launch_bounds__(256) void agg_kernel(
    const unsigned short* __restrict__ m_buf, const float* __restrict__ trans_buf,
    const int* __restrict__ offs, const int* __restrict__ hist,
    float* __restrict__ agg, float* __restrict__ aggc)
{
    const int t = threadIdx.x;
    const int node = blockIdx.x * 4 + (t >> 6);
    const int lane = t & 63;
    if (node >= N_NODES) return;
    const int start = offs[node];
    const int deg = hist[node];
    float a = 0.0f, tc = 0.0f;
    int i = 0;
    for (; i + 4 <= deg; i += 4) {
        const size_t b = (size_t)(start + i) * 64 + lane;
        const float a0 = bf16_to_f(m_buf[b]);
        const float a1 = bf16_to_f(m_buf[b + 64]);
        const float a2 = bf16_to_f(m_buf[b + 128]);
        const float a3 = bf16_to_f(m_buf[b + 192]);
        a += (a0 + a1) + (a2 + a3);
        if (lane < 3) {
            const size_t c = (size_t)(start + i) * 3 + lane;
            tc += (trans_buf[c] + trans_buf[c + 3]) + (trans_buf[c + 6] + trans_buf[c + 9]);
        }
    }
    for (; i < deg; ++i) {
        a += bf16_to_f(m_buf[(size_t)(start + i) * 64 + lane]);
        if (lane < 3) tc += trans_buf[(size_t)(start + i) * 3 + lane];
    }
    agg[(size_t)node * 64 + lane] = a;
    if (lane < 3) aggc[(size_t)node * 3 + lane] = tc;
}

// ============================================================================
// node kernel (round-3 proven version)
// ============================================================================
__global__ __launch_bounds__(256, 2) void egcl_node_mfma(
    const float* __restrict__ h, const float* __restrict__ agg,
    const float* __restrict__ bn1, const float* __restrict__ bn2,
    const unsigned short* __restrict__ Wtn1, const unsigned short* __restrict__ Wtn2,
    float* __restrict__ hout)
{
    __shared__ __align__(16) unsigned short A[128 * 136];
    const int t = threadIdx.x;
    const int wave = t >> 6, L = t & 63;
    const int q = L >> 4, lc = L & 15;
    const int nbase = blockIdx.x * 128;
    const int rbase = wave * 32;

    #pragma unroll 4
    for (int it = 0; it < 16; ++it) {
        const int idx = it * 256 + t;
        const int ln = idx >> 5, part = idx & 31;
        const int node = nbase + ln;
        float4 v = make_float4(0.f, 0.f, 0.f, 0.f);
        if (node < N_NODES) {
            v = (part < 16) ? *(const float4*)(h + (size_t)node * 64 + part * 4)
                            : *(const float4*)(agg + (size_t)node * 64 + (part - 16) * 4);
        }
        *(uint2*)&A[ln * 136 + part * 4] = make_uint2(pack_bf2(v.x, v.y), pack_bf2(v.z, v.w));
    }
    __syncthreads();

    f32x4 acc1[2][4];
    #pragma unroll
    for (int ct = 0; ct < 4; ++ct) {
        const float b = bn1[ct * 16 + lc];
        #pragma unroll
        for (int rt = 0; rt < 2; ++rt)
            #pragma unroll
            for (int i = 0; i < 4; ++i) acc1[rt][ct][i] = b;
    }
    #pragma unroll
    for (int ks = 0; ks < 4; ++ks) {
        bf16x8 af[2];
        #pragma unroll
        for (int rt = 0; rt < 2; ++rt)
            af[rt] = *(const bf16x8*)&A[(rbase + rt * 16 + lc) * 136 + ks * 32 + q * 8];
        #pragma unroll
        for (int ct = 0; ct < 4; ++ct) {
            const bf16x8 bf = *(const bf16x8*)&Wtn1[(ct * 16 + lc) * 128 + ks * 32 + q * 8];
            #pragma unroll
            for (int rt = 0; rt < 2; ++rt)
                acc1[rt][ct] = MFMA16(af[rt], bf, acc1[rt][ct]);
        }
    }
    __syncthreads();

    #pragma unroll
    for (int rt = 0; rt < 2; ++rt)
        #pragma unroll
        for (int ct = 0; ct < 4; ++ct)
            #pragma unroll
            for (int i = 0; i < 4; ++i) {
                const int row = rbase + rt * 16 + q * 4 + i;
                A[row * 72 + ct * 16 + lc] = f2bf(fast_silu(acc1[rt][ct][i]));
            }
    __syncthreads();

    f32x4 acc2[2][4];
    #pragma unroll
    for (int ct = 0; ct < 4; ++ct) {
        const float b = bn2[ct * 16 + lc];
        #pragma unroll
        for (int rt = 0; rt < 2; ++rt)
            #pragma unroll
            for (int i = 0; i < 4; ++i) acc2[rt][ct][i] = b;
    }
    #pragma unroll
    for (int ks = 0; ks < 2; ++ks) {
        bf16x8 af[2];
        #pragma unroll
        for (int rt = 0; rt < 2; ++rt)
            af[rt] = *(const bf16x8*)&A[(rbase + rt * 16 + lc) * 72 + ks * 32 + q * 8];
        #pragma unroll
        for (int ct = 0; ct < 4; ++ct) {
            const bf16x8 bf = *(const bf16x8*)&Wtn2[(ct * 16 + lc) * 64 + ks * 32 + q * 8];
            #pragma unroll
            for (int rt = 0; rt < 2; ++rt)
                acc2[rt][ct] = MFMA16(af[rt], bf, acc2[rt][ct]);
        }
    }

    #pragma unroll
    for (int rt = 0; rt < 2; ++rt)
        #pragma unroll
        for (int ct = 0; ct < 4; ++ct)
            #pragma unroll
            for (int i = 0; i < 4; ++i) {
                const int node = nbase + rbase + rt * 16 + q * 4 + i;
                if (node < N_NODES)
                    hout[(size_t)node * 64 + ct * 16 + lc] = acc2[rt][ct][i];
            }
}

// ============================================================================
// coord output
// ============================================================================
__global__ void coord_kernel_csr(const float* __restrict__ coord,
                                 const float* __restrict__ aggc,
                                 const int* __restrict__ hist,
                                 float* __restrict__ cout)
{
    const int i = blockIdx.x * 256 + threadIdx.x;
    if (i < N_NODES * 3) {
        const int node = i / 3;
        const float c = fmaxf((float)hist[node], 1.0f);
        cout[i] = coord[i] + aggc[i] * __builtin_amdgcn_rcpf(c);
    }
}

// ============================================================================
// launch
// ============================================================================
extern "C" void kernel_launch(void* const* d_in, const int* in_sizes, int n_in,
                              void* d_out, int out_size, void* d_ws, size_t ws_size,
                              hipStream_t stream)
{
    const float* h     = (const float*)d_in[0];
    const float* coord = (const float*)d_in[1];
    const int*   eidx  = (const int*)d_in[2];
    const float* emask = (const float*)d_in[3];
    const float* We1   = (const float*)d_in[4];
    const float* be1   = (const float*)d_in[5];
    const float* We2   = (const float*)d_in[6];
    const float* be2   = (const float*)d_in[7];
    const float* Wn1   = (const float*)d_in[8];
    const float* bn1   = (const float*)d_in[9];
    const float* Wn2   = (const float*)d_in[10];
    const float* bn2   = (const float*)d_in[11];
    const float* Wc1   = (const float*)d_in[12];
    const float* bc1   = (const float*)d_in[13];
    const float* Wc2   = (const float*)d_in[14];

    float* hout = (float*)d_out;
    float* cout = hout + (size_t)N_NODES * 64;

    char* p = (char*)d_ws;
    int* hist = (int*)p;                          p += (size_t)N_NODES * 4;
    int* offs = (int*)p;                          p += (size_t)N_NODES * 4;
    int* pos  = (int*)p;                          p += (size_t)N_NODES * 4;
    int* edge_order = (int*)p;                    p += (size_t)N_EDGES * 4;      // 5.12 MB
    unsigned short* h_bf = (unsigned short*)p;    p += (size_t)N_NODES * 64 * 2; // 5.12 MB
    // agg overlays edge_order + h_bf (dead by the time agg_kernel runs): 10.24 MB exactly
    float* agg = (float*)edge_order;
    unsigned short* m_buf = (unsigned short*)p;   p += (size_t)N_EDGES * 64 * 2; // 163.84 MB
    float* trans_buf = (float*)p;                 p += (size_t)N_EDGES * 3 * 4;  // 15.36 MB
    float* aggc = (float*)p;                      p += (size_t)N_NODES * 3 * 4;  // 0.48 MB
    unsigned short* Wt1  = (unsigned short*)p;    p += 8192 * 2;
    unsigned short* Wt2  = (unsigned short*)p;    p += 4096 * 2;
    unsigned short* Wtc1 = (unsigned short*)p;    p += 4096 * 2;
    unsigned short* Wtn1 = (unsigned short*)p;    p += 8192 * 2;
    unsigned short* Wtn2 = (unsigned short*)p;    p += 4096 * 2;

    hipMemsetAsync(hist, 0, (size_t)N_NODES * 4, stream);
    prep_kernel<<<2612, 256, 0, stream>>>(h, We1, We2, Wc1, Wn1, Wn2,
                                          h_bf, Wt1, Wt2, Wtc1, Wtn1, Wtn2);
    hist_kernel<<<N_EDGES / 1024, 256, 0, stream>>>(eidx, hist);
    scan_kernel<<<1, 1024, 0, stream>>>(hist, offs, pos);
    scatter_kernel<<<N_EDGES / 1024, 256, 0, stream>>>(eidx, pos, edge_order);
    egcl_edge_mfma<<<N_EDGES / 256, 256, 0, stream>>>(
        h_bf, coord, eidx, emask, edge_order,
        We1, be1, be2, bc1, Wc2, Wt1, Wt2, Wtc1, m_buf, trans_buf);
    agg_kernel<<<(N_NODES + 3) / 4, 256, 0, stream>>>(
        m_buf, trans_buf, offs, hist, agg, aggc);
    egcl_node_mfma<<<(N_NODES + 127) / 128, 256, 0, stream>>>(
        h, agg, bn1, bn2, Wtn1, Wtn2, hout);
    coord_kernel_csr<<<(N_NODES * 3 + 255) / 256, 256, 0, stream>>>(
        coord, aggc, hist, cout);
}

// Round 5
// 429.811 us; speedup vs baseline: 11.4040x; 1.0838x over previous
//
#include <hip/hip_runtime.h>
#include <stdint.h>

#define N_NODES 40000
#define N_EDGES 1280000

typedef __attribute__((ext_vector_type(8))) short bf16x8;   // 8 bf16 in 4 VGPRs
typedef __attribute__((ext_vector_type(4))) float f32x4;    // MFMA C/D

#define MFMA16(a, b, c) __builtin_amdgcn_mfma_f32_16x16x32_bf16((a), (b), (c), 0, 0, 0)

// ---------- helpers ----------
__device__ __forceinline__ float fast_silu(float x) {
    float e = __expf(-x);
    return x * __builtin_amdgcn_rcpf(1.0f + e);
}

__device__ __forceinline__ unsigned short f2bf(float x) {
    unsigned int u = __float_as_uint(x);
    u = (u + 0x7FFFu + ((u >> 16) & 1u)) >> 16;
    return (unsigned short)u;
}

__device__ __forceinline__ unsigned int pack_bf2(float a, float b) {
    unsigned int ua = __float_as_uint(a);
    unsigned int ub = __float_as_uint(b);
    ua = (ua + 0x7FFFu + ((ua >> 16) & 1u)) >> 16;
    ub = (ub + 0x7FFFu + ((ub >> 16) & 1u)) & 0xFFFF0000u;
    return (ua & 0xFFFFu) | ub;
}

__device__ __forceinline__ float bf16_to_f(unsigned short s) {
    return __uint_as_float(((unsigned int)s) << 16);
}

// ============================================================================
// prep: pack h -> bf16 and transpose+pack weights (Wt[n][k], contiguous k)
// ============================================================================
__global__ void prep_kernel(const float* __restrict__ h,
                            const float* __restrict__ We1, const float* __restrict__ We2,
                            const float* __restrict__ Wc1, const float* __restrict__ Wn1,
                            const float* __restrict__ Wn2,
                            unsigned short* __restrict__ h_bf,
                            unsigned short* __restrict__ Wt1, unsigned short* __restrict__ Wt2,
                            unsigned short* __restrict__ Wtc1, unsigned short* __restrict__ Wtn1,
                            unsigned short* __restrict__ Wtn2)
{
    const int b = blockIdx.x;
    if (b < 2500) {
        const int i = (b * 256 + threadIdx.x) * 4;   // exactly covers 2,560,000
        const float4 v = *(const float4*)(h + i);
        *(uint2*)(h_bf + i) = make_uint2(pack_bf2(v.x, v.y), pack_bf2(v.z, v.w));
    } else {
        const int t = (b - 2500) * 256 + threadIdx.x;
        if (t < 8192)       { Wt1[t]  = f2bf(We1[(t & 127) * 64 + (t >> 7)]); }
        else if (t < 12288) { int u = t - 8192;  Wt2[u]  = f2bf(We2[(u & 63) * 64 + (u >> 6)]); }
        else if (t < 16384) { int u = t - 12288; Wtc1[u] = f2bf(Wc1[(u & 63) * 64 + (u >> 6)]); }
        else if (t < 24576) { int u = t - 16384; Wtn1[u] = f2bf(Wn1[(u & 127) * 64 + (u >> 7)]); }
        else if (t < 28672) { int u = t - 24576; Wtn2[u] = f2bf(Wn2[(u & 63) * 64 + (u >> 6)]); }
    }
}

// ============================================================================
// CSR prep
// ============================================================================
__global__ void hist_kernel(const int* __restrict__ eidx, int* __restrict__ hist) {
    const int i = (blockIdx.x * 256 + threadIdx.x) * 4;   // 1250 blocks, exact
    const int4 r = *(const int4*)(eidx + i);
    atomicAdd(&hist[r.x], 1);
    atomicAdd(&hist[r.y], 1);
    atomicAdd(&hist[r.z], 1);
    atomicAdd(&hist[r.w], 1);
}

__global__ __launch_bounds__(1024) void scan_kernel(const int* __restrict__ hist,
                                                    int* __restrict__ offs,
                                                    int* __restrict__ pos) {
    __shared__ int wtot[16];
    __shared__ int carry_s;
    const int t = threadIdx.x;
    const int wave = t >> 6, lane = t & 63;
    if (t == 0) carry_s = 0;
    __syncthreads();
    for (int base = 0; base < N_NODES; base += 8192) {
        const int idx = base + t * 8;
        int v[8];
        if (idx + 8 <= N_NODES) {
            const int4 a = *(const int4*)(hist + idx);
            const int4 b = *(const int4*)(hist + idx + 4);
            v[0] = a.x; v[1] = a.y; v[2] = a.z; v[3] = a.w;
            v[4] = b.x; v[5] = b.y; v[6] = b.z; v[7] = b.w;
        } else {
            #pragma unroll
            for (int j = 0; j < 8; ++j) v[j] = (idx + j < N_NODES) ? hist[idx + j] : 0;
        }
        int s = 0;
        #pragma unroll
        for (int j = 0; j < 8; ++j) s += v[j];
        int S = s;
        #pragma unroll
        for (int d = 1; d < 64; d <<= 1) {
            const int u = __shfl_up(S, d, 64);
            if (lane >= d) S += u;
        }
        if (lane == 63) wtot[wave] = S;
        __syncthreads();
        if (wave == 0 && lane < 16) {
            int w = wtot[lane];
            #pragma unroll
            for (int d = 1; d < 16; d <<= 1) {
                const int u = __shfl_up(w, d, 64);
                if (lane >= d) w += u;
            }
            wtot[lane] = w;
        }
        __syncthreads();
        const int wb = (wave == 0) ? 0 : wtot[wave - 1];
        int run = carry_s + wb + (S - s);
        #pragma unroll
        for (int j = 0; j < 8; ++j) {
            if (idx + j < N_NODES) { offs[idx + j] = run; pos[idx + j] = run; }
            run += v[j];
        }
        __syncthreads();
        if (t == 0) carry_s += wtot[15];
        __syncthreads();
    }
}

__global__ void scatter_kernel(const int* __restrict__ eidx,
                               int* __restrict__ pos, int* __restrict__ edge_order,
                               int* __restrict__ slot2node) {
    const int i = (blockIdx.x * 256 + threadIdx.x) * 4;
    const int4 r = *(const int4*)(eidx + i);
    const int s0 = atomicAdd(&pos[r.x], 1); edge_order[s0] = i + 0; slot2node[s0] = r.x;
    const int s1 = atomicAdd(&pos[r.y], 1); edge_order[s1] = i + 1; slot2node[s1] = r.y;
    const int s2 = atomicAdd(&pos[r.z], 1); edge_order[s2] = i + 2; slot2node[s2] = r.z;
    const int s3 = atomicAdd(&pos[r.w], 1); edge_order[s3] = i + 3; slot2node[s3] = r.w;
}

// ============================================================================
// edge kernel: CSR-ordered, transposed-MFMA, FUSED aggregation.
// Block = 256 CSR slots, 4 waves; wave owns 64 slots for the MLP phase.
// After m is complete in LDS (single barrier), waves do a segmented reduction
// over the block's node ranges: interior nodes -> direct store, boundary
// nodes (<=2/block) -> fp32 atomicAdd. m never touches global memory.
// ============================================================================
__global__ __launch_bounds__(256, 3) void egcl_edge_mfma(
    const unsigned short* __restrict__ h_bf, const float* __restrict__ coord,
    const int* __restrict__ eidx, const float* __restrict__ emask,
    const int* __restrict__ edge_order, const int* __restrict__ slot2node,
    const int* __restrict__ offs_g, const int* __restrict__ hist_g,
    const float* __restrict__ We1, const float* __restrict__ be1,
    const float* __restrict__ be2, const float* __restrict__ bc1,
    const float* __restrict__ Wc2,
    const unsigned short* __restrict__ Wt1, const unsigned short* __restrict__ Wt2,
    const unsigned short* __restrict__ Wtc1,
    float* __restrict__ agg, float* __restrict__ aggc)
{
    __shared__ __align__(16) unsigned short A[256 * 72];
    __shared__ float rad_s[256];
    __shared__ float dif_s[768];
    __shared__ float msk_s[256];
    __shared__ float cval_s[256];
    __shared__ int ri_s[256];
    __shared__ int ci_s[256];
    __shared__ int sn_s[256];

    const int t = threadIdx.x;
    const int w = t >> 6, L = t & 63;
    const int q = L >> 4, lc = L & 15;
    const int ebase = blockIdx.x * 256;
    const int rbase = w * 64;

    // ---- meta: one CSR slot per thread (slot t is in this thread's own wave) ----
    {
        const int e = edge_order[ebase + t];
        const int r = eidx[e];
        const int c = eidx[N_EDGES + e];
        ri_s[t] = r; ci_s[t] = c; sn_s[t] = r;
        const float d0 = coord[r * 3 + 0] - coord[c * 3 + 0];
        const float d1 = coord[r * 3 + 1] - coord[c * 3 + 1];
        const float d2 = coord[r * 3 + 2] - coord[c * 3 + 2];
        dif_s[t * 3 + 0] = d0; dif_s[t * 3 + 1] = d1; dif_s[t * 3 + 2] = d2;
        rad_s[t] = d0 * d0 + d1 * d1 + d2 * d2;
        msk_s[t] = emask[e];
    }

    // ---- stage h_bf[row] (k = 0..63), wave-private rows ----
    #pragma unroll
    for (int it = 0; it < 8; ++it) {
        const int j = it * 64 + L;
        const int row = rbase + (j >> 3);
        const int part = j & 7;
        const bf16x8 v = *(const bf16x8*)(h_bf + (size_t)ri_s[row] * 64 + part * 8);
        *(bf16x8*)&A[row * 72 + part * 8] = v;
    }

    // ---- layer1 init: C^T[out][edge] = be1[out] + radial[edge]*We1[128][out] ----
    f32x4 acc[4][4];   // [ot][et]
    #pragma unroll
    for (int ot = 0; ot < 4; ++ot) {
        const float4 bv = *(const float4*)(be1 + ot * 16 + q * 4);
        const float4 wv = *(const float4*)(We1 + 128 * 64 + ot * 16 + q * 4);
        #pragma unroll
        for (int et = 0; et < 4; ++et) {
            const float rad = rad_s[rbase + et * 16 + lc];
            acc[ot][et][0] = fmaf(rad, wv.x, bv.x);
            acc[ot][et][1] = fmaf(rad, wv.y, bv.y);
            acc[ot][et][2] = fmaf(rad, wv.z, bv.z);
            acc[ot][et][3] = fmaf(rad, wv.w, bv.w);
        }
    }

    // ---- layer1 MFMA, k = 0..63 (h[row]) ----
    #pragma unroll
    for (int ks = 0; ks < 2; ++ks) {
        bf16x8 bfr[4];
        #pragma unroll
        for (int et = 0; et < 4; ++et)
            bfr[et] = *(const bf16x8*)&A[(rbase + et * 16 + lc) * 72 + ks * 32 + q * 8];
        #pragma unroll
        for (int ot = 0; ot < 4; ++ot) {
            const bf16x8 af = *(const bf16x8*)&Wt1[(ot * 16 + lc) * 128 + ks * 32 + q * 8];
            #pragma unroll
            for (int et = 0; et < 4; ++et)
                acc[ot][et] = MFMA16(af, bfr[et], acc[ot][et]);
        }
    }

    // ---- restage h_bf[col] over A (own rows only) ----
    #pragma unroll
    for (int it = 0; it < 8; ++it) {
        const int j = it * 64 + L;
        const int row = rbase + (j >> 3);
        const int part = j & 7;
        const bf16x8 v = *(const bf16x8*)(h_bf + (size_t)ci_s[row] * 64 + part * 8);
        *(bf16x8*)&A[row * 72 + part * 8] = v;
    }

    // ---- layer1 MFMA, k = 64..127 (h[col]) ----
    #pragma unroll
    for (int ks = 0; ks < 2; ++ks) {
        bf16x8 bfr[4];
        #pragma unroll
        for (int et = 0; et < 4; ++et)
            bfr[et] = *(const bf16x8*)&A[(rbase + et * 16 + lc) * 72 + ks * 32 + q * 8];
        #pragma unroll
        for (int ot = 0; ot < 4; ++ot) {
            const bf16x8 af = *(const bf16x8*)&Wt1[(ot * 16 + lc) * 128 + 64 + ks * 32 + q * 8];
            #pragma unroll
            for (int et = 0; et < 4; ++et)
                acc[ot][et] = MFMA16(af, bfr[et], acc[ot][et]);
        }
    }

    // ---- m1 = silu -> A row-major (packed b64 writes, 4 consecutive channels) ----
    #pragma unroll
    for (int et = 0; et < 4; ++et) {
        const int row = rbase + et * 16 + lc;
        #pragma unroll
        for (int ot = 0; ot < 4; ++ot) {
            uint2 p;
            p.x = pack_bf2(fast_silu(acc[ot][et][0]), fast_silu(acc[ot][et][1]));
            p.y = pack_bf2(fast_silu(acc[ot][et][2]), fast_silu(acc[ot][et][3]));
            *(uint2*)&A[row * 72 + ot * 16 + q * 4] = p;
        }
    }

    // ---- layer2 ----
    f32x4 acc2[4][4];
    #pragma unroll
    for (int ot = 0; ot < 4; ++ot) {
        const float4 bv = *(const float4*)(be2 + ot * 16 + q * 4);
        #pragma unroll
        for (int et = 0; et < 4; ++et) {
            acc2[ot][et][0] = bv.x; acc2[ot][et][1] = bv.y;
            acc2[ot][et][2] = bv.z; acc2[ot][et][3] = bv.w;
        }
    }
    #pragma unroll
    for (int ks = 0; ks < 2; ++ks) {
        bf16x8 bfr[4];
        #pragma unroll
        for (int et = 0; et < 4; ++et)
            bfr[et] = *(const bf16x8*)&A[(rbase + et * 16 + lc) * 72 + ks * 32 + q * 8];
        #pragma unroll
        for (int ot = 0; ot < 4; ++ot) {
            const bf16x8 af = *(const bf16x8*)&Wt2[(ot * 16 + lc) * 64 + ks * 32 + q * 8];
            #pragma unroll
            for (int et = 0; et < 4; ++et)
                acc2[ot][et] = MFMA16(af, bfr[et], acc2[ot][et]);
        }
    }

    // ---- m = silu * mask -> A ----
    #pragma unroll
    for (int et = 0; et < 4; ++et) {
        const int row = rbase + et * 16 + lc;
        const float mk = msk_s[row];
        #pragma unroll
        for (int ot = 0; ot < 4; ++ot) {
            uint2 p;
            p.x = pack_bf2(fast_silu(acc2[ot][et][0]) * mk, fast_silu(acc2[ot][et][1]) * mk);
            p.y = pack_bf2(fast_silu(acc2[ot][et][2]) * mk, fast_silu(acc2[ot][et][3]) * mk);
            *(uint2*)&A[row * 72 + ot * 16 + q * 4] = p;
        }
    }

    // ---- coord mlp ----
    f32x4 acc3[4][4];
    #pragma unroll
    for (int ot = 0; ot < 4; ++ot) {
        const float4 bv = *(const float4*)(bc1 + ot * 16 + q * 4);
        #pragma unroll
        for (int et = 0; et < 4; ++et) {
            acc3[ot][et][0] = bv.x; acc3[ot][et][1] = bv.y;
            acc3[ot][et][2] = bv.z; acc3[ot][et][3] = bv.w;
        }
    }
    #pragma unroll
    for (int ks = 0; ks < 2; ++ks) {
        bf16x8 bfr[4];
        #pragma unroll
        for (int et = 0; et < 4; ++et)
            bfr[et] = *(const bf16x8*)&A[(rbase + et * 16 + lc) * 72 + ks * 32 + q * 8];
        #pragma unroll
        for (int ot = 0; ot < 4; ++ot) {
            const bf16x8 af = *(const bf16x8*)&Wtc1[(ot * 16 + lc) * 64 + ks * 32 + q * 8];
            #pragma unroll
            for (int et = 0; et < 4; ++et)
                acc3[ot][et] = MFMA16(af, bfr[et], acc3[ot][et]);
        }
    }
    // final dot with Wc2: sum over out-channels, reduce across q groups;
    // fold mask so cval_s holds c*mask per slot
    {
        float4 wv[4];
        #pragma unroll
        for (int ot = 0; ot < 4; ++ot) wv[ot] = *(const float4*)(Wc2 + ot * 16 + q * 4);
        #pragma unroll
        for (int et = 0; et < 4; ++et) {
            float s = 0.0f;
            #pragma unroll
            for (int ot = 0; ot < 4; ++ot) {
                s = fmaf(fast_silu(acc3[ot][et][0]), wv[ot].x, s);
                s = fmaf(fast_silu(acc3[ot][et][1]), wv[ot].y, s);
                s = fmaf(fast_silu(acc3[ot][et][2]), wv[ot].z, s);
                s = fmaf(fast_silu(acc3[ot][et][3]), wv[ot].w, s);
            }
            s += __shfl_xor(s, 16, 64);
            s += __shfl_xor(s, 32, 64);
            if (q == 0) {
                const int row = rbase + et * 16 + lc;
                cval_s[row] = s * msk_s[row];
            }
        }
    }

    __syncthreads();   // whole block's m / cval / dif now valid

    // ---- fused segmented aggregation over this block's node ranges ----
    // wave handles nodes n0+w, n0+w+4, ...; lane = channel.
    {
        const int n0 = sn_s[0], n1 = sn_s[255];
        for (int n = n0 + w; n <= n1; n += 4) {
            const int os = offs_g[n];
            const int dg = hist_g[n];
            const int s0 = max(os - ebase, 0);
            const int s1 = min(os + dg - ebase, 256);
            float s = 0.0f;
            for (int slot = s0; slot < s1; ++slot)
                s += bf16_to_f(A[slot * 72 + L]);
            float t3 = 0.0f;
            if (L < 3) {
                for (int slot = s0; slot < s1; ++slot)
                    t3 = fmaf(dif_s[slot * 3 + L], cval_s[slot], t3);
            }
            const bool interior = (os >= ebase) && (os + dg <= ebase + 256);
            if (interior) {
                agg[(size_t)n * 64 + L] = s;
                if (L < 3) aggc[n * 3 + L] = t3;
            } else {
                atomicAdd(&agg[(size_t)n * 64 + L], s);
                if (L < 3) atomicAdd(&aggc[n * 3 + L], t3);
            }
        }
    }
}

// ============================================================================
// node kernel
// ============================================================================
__global__ __launch_bounds__(256, 2) void egcl_node_mfma(
    const float* __restrict__ h, const float* __restrict__ agg,
    const float* __restrict__ bn1, const float* __restrict__ bn2,
    const unsigned short* __restrict__ Wtn1, const unsigned short* __restrict__ Wtn2,
    float* __restrict__ hout)
{
    __shared__ __align__(16) unsigned short A[128 * 136];
    const int t = threadIdx.x;
    const int wave = t >> 6, L = t & 63;
    const int q = L >> 4, lc = L & 15;
    const int nbase = blockIdx.x * 128;
    const int rbase = wave * 32;

    #pragma unroll 4
    for (int it = 0; it < 16; ++it) {
        const int idx = it * 256 + t;
        const int ln = idx >> 5, part = idx & 31;
        const int node = nbase + ln;
        float4 v = make_float4(0.f, 0.f, 0.f, 0.f);
        if (node < N_NODES) {
            v = (part < 16) ? *(const float4*)(h + (size_t)node * 64 + part * 4)
                            : *(const float4*)(agg + (size_t)node * 64 + (part - 16) * 4);
        }
        *(uint2*)&A[ln * 136 + part * 4] = make_uint2(pack_bf2(v.x, v.y), pack_bf2(v.z, v.w));
    }
    __syncthreads();

    f32x4 acc1[2][4];
    #pragma unroll
    for (int ct = 0; ct < 4; ++ct) {
        const float b = bn1[ct * 16 + lc];
        #pragma unroll
        for (int rt = 0; rt < 2; ++rt)
            #pragma unroll
            for (int i = 0; i < 4; ++i) acc1[rt][ct][i] = b;
    }
    #pragma unroll
    for (int ks = 0; ks < 4; ++ks) {
        bf16x8 af[2];
        #pragma unroll
        for (int rt = 0; rt < 2; ++rt)
            af[rt] = *(const bf16x8*)&A[(rbase + rt * 16 + lc) * 136 + ks * 32 + q * 8];
        #pragma unroll
        for (int ct = 0; ct < 4; ++ct) {
            const bf16x8 bf = *(const bf16x8*)&Wtn1[(ct * 16 + lc) * 128 + ks * 32 + q * 8];
            #pragma unroll
            for (int rt = 0; rt < 2; ++rt)
                acc1[rt][ct] = MFMA16(af[rt], bf, acc1[rt][ct]);
        }
    }
    __syncthreads();

    #pragma unroll
    for (int rt = 0; rt < 2; ++rt)
        #pragma unroll
        for (int ct = 0; ct < 4; ++ct)
            #pragma unroll
            for (int i = 0; i < 4; ++i) {
                const int row = rbase + rt * 16 + q * 4 + i;
                A[row * 72 + ct * 16 + lc] = f2bf(fast_silu(acc1[rt][ct][i]));
            }
    __syncthreads();

    f32x4 acc2[2][4];
    #pragma unroll
    for (int ct = 0; ct < 4; ++ct) {
        const float b = bn2[ct * 16 + lc];
        #pragma unroll
        for (int rt = 0; rt < 2; ++rt)
            #pragma unroll
            for (int i = 0; i < 4; ++i) acc2[rt][ct][i] = b;
    }
    #pragma unroll
    for (int ks = 0; ks < 2; ++ks) {
        bf16x8 af[2];
        #pragma unroll
        for (int rt = 0; rt < 2; ++rt)
            af[rt] = *(const bf16x8*)&A[(rbase + rt * 16 + lc) * 72 + ks * 32 + q * 8];
        #pragma unroll
        for (int ct = 0; ct < 4; ++ct) {
            const bf16x8 bf = *(const bf16x8*)&Wtn2[(ct * 16 + lc) * 64 + ks * 32 + q * 8];
            #pragma unroll
            for (int rt = 0; rt < 2; ++rt)
                acc2[rt][ct] = MFMA16(af[rt], bf, acc2[rt][ct]);
        }
    }

    #pragma unroll
    for (int rt = 0; rt < 2; ++rt)
        #pragma unroll
        for (int ct = 0; ct < 4; ++ct)
            #pragma unroll
            for (int i = 0; i < 4; ++i) {
                const int node = nbase + rbase + rt * 16 + q * 4 + i;
                if (node < N_NODES)
                    hout[(size_t)node * 64 + ct * 16 + lc] = acc2[rt][ct][i];
            }
}

// ============================================================================
// coord output
// ============================================================================
__global__ void coord_kernel_csr(const float* __restrict__ coord,
                                 const float* __restrict__ aggc,
                                 const int* __restrict__ hist,
                                 float* __restrict__ cout)
{
    const int i = blockIdx.x * 256 + threadIdx.x;
    if (i < N_NODES * 3) {
        const int node = i / 3;
        const float c = fmaxf((float)hist[node], 1.0f);
        cout[i] = coord[i] + aggc[i] * __builtin_amdgcn_rcpf(c);
    }
}

// ============================================================================
// launch
// ============================================================================
extern "C" void kernel_launch(void* const* d_in, const int* in_sizes, int n_in,
                              void* d_out, int out_size, void* d_ws, size_t ws_size,
                              hipStream_t stream)
{
    const float* h     = (const float*)d_in[0];
    const float* coord = (const float*)d_in[1];
    const int*   eidx  = (const int*)d_in[2];
    const float* emask = (const float*)d_in[3];
    const float* We1   = (const float*)d_in[4];
    const float* be1   = (const float*)d_in[5];
    const float* We2   = (const float*)d_in[6];
    const float* be2   = (const float*)d_in[7];
    const float* Wn1   = (const float*)d_in[8];
    const float* bn1   = (const float*)d_in[9];
    const float* Wn2   = (const float*)d_in[10];
    const float* bn2   = (const float*)d_in[11];
    const float* Wc1   = (const float*)d_in[12];
    const float* bc1   = (const float*)d_in[13];
    const float* Wc2   = (const float*)d_in[14];

    float* hout = (float*)d_out;
    float* cout = hout + (size_t)N_NODES * 64;

    // ws layout: [agg | aggc | hist] contiguous for a single zeroing memset,
    // then CSR arrays, packed inputs, packed weights.
    char* p = (char*)d_ws;
    float* agg  = (float*)p;                      p += (size_t)N_NODES * 64 * 4; // 10.24 MB
    float* aggc = (float*)p;                      p += (size_t)N_NODES * 3 * 4;  // 0.48 MB
    int* hist   = (int*)p;                        p += (size_t)N_NODES * 4;      // 0.16 MB
    int* offs   = (int*)p;                        p += (size_t)N_NODES * 4;
    int* pos    = (int*)p;                        p += (size_t)N_NODES * 4;
    int* edge_order = (int*)p;                    p += (size_t)N_EDGES * 4;      // 5.12 MB
    int* slot2node  = (int*)p;                    p += (size_t)N_EDGES * 4;      // 5.12 MB
    unsigned short* h_bf = (unsigned short*)p;    p += (size_t)N_NODES * 64 * 2; // 5.12 MB
    unsigned short* Wt1  = (unsigned short*)p;    p += 8192 * 2;
    unsigned short* Wt2  = (unsigned short*)p;    p += 4096 * 2;
    unsigned short* Wtc1 = (unsigned short*)p;    p += 4096 * 2;
    unsigned short* Wtn1 = (unsigned short*)p;    p += 8192 * 2;
    unsigned short* Wtn2 = (unsigned short*)p;    p += 4096 * 2;

    // zero agg + aggc + hist in one shot (10.88 MB)
    hipMemsetAsync(agg, 0, (size_t)N_NODES * 68 * 4, stream);
    prep_kernel<<<2612, 256, 0, stream>>>(h, We1, We2, Wc1, Wn1, Wn2,
                                          h_bf, Wt1, Wt2, Wtc1, Wtn1, Wtn2);
    hist_kernel<<<N_EDGES / 1024, 256, 0, stream>>>(eidx, hist);
    scan_kernel<<<1, 1024, 0, stream>>>(hist, offs, pos);
    scatter_kernel<<<N_EDGES / 1024, 256, 0, stream>>>(eidx, pos, edge_order, slot2node);
    egcl_edge_mfma<<<N_EDGES / 256, 256, 0, stream>>>(
        h_bf, coord, eidx, emask, edge_order, slot2node, offs, hist,
        We1, be1, be2, bc1, Wc2, Wt1, Wt2, Wtc1, agg, aggc);
    egcl_node_mfma<<<(N_NODES + 127) / 128, 256, 0, stream>>>(
        h, agg, bn1, bn2, Wtn1, Wtn2, hout);
    coord_kernel_csr<<<(N_NODES * 3 + 255) / 256, 256, 0, stream>>>(
        coord, aggc, hist, cout);
}

// Round 6
// 417.522 us; speedup vs baseline: 11.7397x; 1.0294x over previous
//
#include <hip/hip_runtime.h>
#include <stdint.h>

#define N_NODES 40000
#define N_EDGES 1280000
#define NODE_BLOCKS 313   // ceil(40000/128)

typedef __attribute__((ext_vector_type(8))) short bf16x8;   // 8 bf16 in 4 VGPRs
typedef __attribute__((ext_vector_type(4))) float f32x4;    // MFMA C/D

#define MFMA16(a, b, c) __builtin_amdgcn_mfma_f32_16x16x32_bf16((a), (b), (c), 0, 0, 0)

// ---------- helpers ----------
__device__ __forceinline__ float fast_silu(float x) {
    float e = __expf(-x);
    return x * __builtin_amdgcn_rcpf(1.0f + e);
}

__device__ __forceinline__ unsigned short f2bf(float x) {
    unsigned int u = __float_as_uint(x);
    u = (u + 0x7FFFu + ((u >> 16) & 1u)) >> 16;
    return (unsigned short)u;
}

__device__ __forceinline__ unsigned int pack_bf2(float a, float b) {
    unsigned int ua = __float_as_uint(a);
    unsigned int ub = __float_as_uint(b);
    ua = (ua + 0x7FFFu + ((ua >> 16) & 1u)) >> 16;
    ub = (ub + 0x7FFFu + ((ub >> 16) & 1u)) & 0xFFFF0000u;
    return (ua & 0xFFFFu) | ub;
}

__device__ __forceinline__ float bf16_to_f(unsigned short s) {
    return __uint_as_float(((unsigned int)s) << 16);
}

// ============================================================================
// prep + hist fused: blocks [0,2500) pack h; [2500,2612) pack weights;
// [2612,3862) histogram rows.
// ============================================================================
__global__ void prep_hist_kernel(const float* __restrict__ h,
                                 const float* __restrict__ We1, const float* __restrict__ We2,
                                 const float* __restrict__ Wc1, const float* __restrict__ Wn1,
                                 const float* __restrict__ Wn2,
                                 const int* __restrict__ eidx,
                                 unsigned short* __restrict__ h_bf,
                                 unsigned short* __restrict__ Wt1, unsigned short* __restrict__ Wt2,
                                 unsigned short* __restrict__ Wtc1, unsigned short* __restrict__ Wtn1,
                                 unsigned short* __restrict__ Wtn2,
                                 int* __restrict__ hist)
{
    const int b = blockIdx.x;
    if (b < 2500) {
        const int i = (b * 256 + threadIdx.x) * 4;   // exactly covers 2,560,000
        const float4 v = *(const float4*)(h + i);
        *(uint2*)(h_bf + i) = make_uint2(pack_bf2(v.x, v.y), pack_bf2(v.z, v.w));
    } else if (b < 2612) {
        const int t = (b - 2500) * 256 + threadIdx.x;
        if (t < 8192)       { Wt1[t]  = f2bf(We1[(t & 127) * 64 + (t >> 7)]); }
        else if (t < 12288) { int u = t - 8192;  Wt2[u]  = f2bf(We2[(u & 63) * 64 + (u >> 6)]); }
        else if (t < 16384) { int u = t - 12288; Wtc1[u] = f2bf(Wc1[(u & 63) * 64 + (u >> 6)]); }
        else if (t < 24576) { int u = t - 16384; Wtn1[u] = f2bf(Wn1[(u & 127) * 64 + (u >> 7)]); }
        else if (t < 28672) { int u = t - 24576; Wtn2[u] = f2bf(Wn2[(u & 63) * 64 + (u >> 6)]); }
    } else {
        const int i = ((b - 2612) * 256 + threadIdx.x) * 4;   // 1250 blocks, exact
        const int4 r = *(const int4*)(eidx + i);
        atomicAdd(&hist[r.x], 1);
        atomicAdd(&hist[r.y], 1);
        atomicAdd(&hist[r.z], 1);
        atomicAdd(&hist[r.w], 1);
    }
}

// ============================================================================
// single-block scan
// ============================================================================
__global__ __launch_bounds__(1024) void scan_kernel(const int* __restrict__ hist,
                                                    int* __restrict__ offs,
                                                    int* __restrict__ pos) {
    __shared__ int wtot[16];
    __shared__ int carry_s;
    const int t = threadIdx.x;
    const int wave = t >> 6, lane = t & 63;
    if (t == 0) carry_s = 0;
    __syncthreads();
    for (int base = 0; base < N_NODES; base += 8192) {
        const int idx = base + t * 8;
        int v[8];
        if (idx + 8 <= N_NODES) {
            const int4 a = *(const int4*)(hist + idx);
            const int4 b = *(const int4*)(hist + idx + 4);
            v[0] = a.x; v[1] = a.y; v[2] = a.z; v[3] = a.w;
            v[4] = b.x; v[5] = b.y; v[6] = b.z; v[7] = b.w;
        } else {
            #pragma unroll
            for (int j = 0; j < 8; ++j) v[j] = (idx + j < N_NODES) ? hist[idx + j] : 0;
        }
        int s = 0;
        #pragma unroll
        for (int j = 0; j < 8; ++j) s += v[j];
        int S = s;
        #pragma unroll
        for (int d = 1; d < 64; d <<= 1) {
            const int u = __shfl_up(S, d, 64);
            if (lane >= d) S += u;
        }
        if (lane == 63) wtot[wave] = S;
        __syncthreads();
        if (wave == 0 && lane < 16) {
            int w = wtot[lane];
            #pragma unroll
            for (int d = 1; d < 16; d <<= 1) {
                const int u = __shfl_up(w, d, 64);
                if (lane >= d) w += u;
            }
            wtot[lane] = w;
        }
        __syncthreads();
        const int wb = (wave == 0) ? 0 : wtot[wave - 1];
        int run = carry_s + wb + (S - s);
        #pragma unroll
        for (int j = 0; j < 8; ++j) {
            if (idx + j < N_NODES) { offs[idx + j] = run; pos[idx + j] = run; }
            run += v[j];
        }
        __syncthreads();
        if (t == 0) carry_s += wtot[15];
        __syncthreads();
    }
}

// ============================================================================
// scatter: one 16 B payload {row, col, mask, 0} per CSR slot (1 line/edge)
// ============================================================================
__global__ void scatter_kernel(const int* __restrict__ eidx, const float* __restrict__ emask,
                               int* __restrict__ pos, int4* __restrict__ payload) {
    const int i = (blockIdx.x * 256 + threadIdx.x) * 4;
    const int4 r = *(const int4*)(eidx + i);
    const int4 c = *(const int4*)(eidx + N_EDGES + i);
    const float4 mk = *(const float4*)(emask + i);
    const int s0 = atomicAdd(&pos[r.x], 1); payload[s0] = make_int4(r.x, c.x, __float_as_int(mk.x), 0);
    const int s1 = atomicAdd(&pos[r.y], 1); payload[s1] = make_int4(r.y, c.y, __float_as_int(mk.y), 0);
    const int s2 = atomicAdd(&pos[r.z], 1); payload[s2] = make_int4(r.z, c.z, __float_as_int(mk.z), 0);
    const int s3 = atomicAdd(&pos[r.w], 1); payload[s3] = make_int4(r.w, c.w, __float_as_int(mk.w), 0);
}

// ============================================================================
// edge kernel: CSR payload, transposed-MFMA, fused aggregation (one barrier)
// ============================================================================
__global__ __launch_bounds__(256, 3) void egcl_edge_mfma(
    const unsigned short* __restrict__ h_bf, const float* __restrict__ coord,
    const int4* __restrict__ payload,
    const int* __restrict__ offs_g, const int* __restrict__ hist_g,
    const float* __restrict__ We1, const float* __restrict__ be1,
    const float* __restrict__ be2, const float* __restrict__ bc1,
    const float* __restrict__ Wc2,
    const unsigned short* __restrict__ Wt1, const unsigned short* __restrict__ Wt2,
    const unsigned short* __restrict__ Wtc1,
    float* __restrict__ agg, float* __restrict__ aggc)
{
    __shared__ __align__(16) unsigned short A[256 * 72];
    __shared__ float rad_s[256];
    __shared__ float dif_s[768];
    __shared__ float msk_s[256];
    __shared__ float cval_s[256];
    __shared__ int ri_s[256];
    __shared__ int ci_s[256];

    const int t = threadIdx.x;
    const int w = t >> 6, L = t & 63;
    const int q = L >> 4, lc = L & 15;
    const int ebase = blockIdx.x * 256;
    const int rbase = w * 64;

    // ---- meta: one coalesced payload read per slot ----
    {
        const int4 pl = payload[ebase + t];
        const int r = pl.x, c = pl.y;
        ri_s[t] = r; ci_s[t] = c;
        msk_s[t] = __int_as_float(pl.z);
        const float d0 = coord[r * 3 + 0] - coord[c * 3 + 0];
        const float d1 = coord[r * 3 + 1] - coord[c * 3 + 1];
        const float d2 = coord[r * 3 + 2] - coord[c * 3 + 2];
        dif_s[t * 3 + 0] = d0; dif_s[t * 3 + 1] = d1; dif_s[t * 3 + 2] = d2;
        rad_s[t] = d0 * d0 + d1 * d1 + d2 * d2;
    }

    // ---- stage h_bf[row] (k = 0..63), wave-private rows ----
    #pragma unroll
    for (int it = 0; it < 8; ++it) {
        const int j = it * 64 + L;
        const int row = rbase + (j >> 3);
        const int part = j & 7;
        const bf16x8 v = *(const bf16x8*)(h_bf + (size_t)ri_s[row] * 64 + part * 8);
        *(bf16x8*)&A[row * 72 + part * 8] = v;
    }

    // ---- layer1 init ----
    f32x4 acc[4][4];   // [ot][et]
    #pragma unroll
    for (int ot = 0; ot < 4; ++ot) {
        const float4 bv = *(const float4*)(be1 + ot * 16 + q * 4);
        const float4 wv = *(const float4*)(We1 + 128 * 64 + ot * 16 + q * 4);
        #pragma unroll
        for (int et = 0; et < 4; ++et) {
            const float rad = rad_s[rbase + et * 16 + lc];
            acc[ot][et][0] = fmaf(rad, wv.x, bv.x);
            acc[ot][et][1] = fmaf(rad, wv.y, bv.y);
            acc[ot][et][2] = fmaf(rad, wv.z, bv.z);
            acc[ot][et][3] = fmaf(rad, wv.w, bv.w);
        }
    }

    // ---- layer1 MFMA, k = 0..63 (h[row]) ----
    #pragma unroll
    for (int ks = 0; ks < 2; ++ks) {
        bf16x8 bfr[4];
        #pragma unroll
        for (int et = 0; et < 4; ++et)
            bfr[et] = *(const bf16x8*)&A[(rbase + et * 16 + lc) * 72 + ks * 32 + q * 8];
        #pragma unroll
        for (int ot = 0; ot < 4; ++ot) {
            const bf16x8 af = *(const bf16x8*)&Wt1[(ot * 16 + lc) * 128 + ks * 32 + q * 8];
            #pragma unroll
            for (int et = 0; et < 4; ++et)
                acc[ot][et] = MFMA16(af, bfr[et], acc[ot][et]);
        }
    }

    // ---- restage h_bf[col] ----
    #pragma unroll
    for (int it = 0; it < 8; ++it) {
        const int j = it * 64 + L;
        const int row = rbase + (j >> 3);
        const int part = j & 7;
        const bf16x8 v = *(const bf16x8*)(h_bf + (size_t)ci_s[row] * 64 + part * 8);
        *(bf16x8*)&A[row * 72 + part * 8] = v;
    }

    // ---- layer1 MFMA, k = 64..127 (h[col]) ----
    #pragma unroll
    for (int ks = 0; ks < 2; ++ks) {
        bf16x8 bfr[4];
        #pragma unroll
        for (int et = 0; et < 4; ++et)
            bfr[et] = *(const bf16x8*)&A[(rbase + et * 16 + lc) * 72 + ks * 32 + q * 8];
        #pragma unroll
        for (int ot = 0; ot < 4; ++ot) {
            const bf16x8 af = *(const bf16x8*)&Wt1[(ot * 16 + lc) * 128 + 64 + ks * 32 + q * 8];
            #pragma unroll
            for (int et = 0; et < 4; ++et)
                acc[ot][et] = MFMA16(af, bfr[et], acc[ot][et]);
        }
    }

    // ---- m1 = silu -> A ----
    #pragma unroll
    for (int et = 0; et < 4; ++et) {
        const int row = rbase + et * 16 + lc;
        #pragma unroll
        for (int ot = 0; ot < 4; ++ot) {
            uint2 p;
            p.x = pack_bf2(fast_silu(acc[ot][et][0]), fast_silu(acc[ot][et][1]));
            p.y = pack_bf2(fast_silu(acc[ot][et][2]), fast_silu(acc[ot][et][3]));
            *(uint2*)&A[row * 72 + ot * 16 + q * 4] = p;
        }
    }

    // ---- layer2 ----
    f32x4 acc2[4][4];
    #pragma unroll
    for (int ot = 0; ot < 4; ++ot) {
        const float4 bv = *(const float4*)(be2 + ot * 16 + q * 4);
        #pragma unroll
        for (int et = 0; et < 4; ++et) {
            acc2[ot][et][0] = bv.x; acc2[ot][et][1] = bv.y;
            acc2[ot][et][2] = bv.z; acc2[ot][et][3] = bv.w;
        }
    }
    #pragma unroll
    for (int ks = 0; ks < 2; ++ks) {
        bf16x8 bfr[4];
        #pragma unroll
        for (int et = 0; et < 4; ++et)
            bfr[et] = *(const bf16x8*)&A[(rbase + et * 16 + lc) * 72 + ks * 32 + q * 8];
        #pragma unroll
        for (int ot = 0; ot < 4; ++ot) {
            const bf16x8 af = *(const bf16x8*)&Wt2[(ot * 16 + lc) * 64 + ks * 32 + q * 8];
            #pragma unroll
            for (int et = 0; et < 4; ++et)
                acc2[ot][et] = MFMA16(af, bfr[et], acc2[ot][et]);
        }
    }

    // ---- m = silu * mask -> A ----
    #pragma unroll
    for (int et = 0; et < 4; ++et) {
        const int row = rbase + et * 16 + lc;
        const float mk = msk_s[row];
        #pragma unroll
        for (int ot = 0; ot < 4; ++ot) {
            uint2 p;
            p.x = pack_bf2(fast_silu(acc2[ot][et][0]) * mk, fast_silu(acc2[ot][et][1]) * mk);
            p.y = pack_bf2(fast_silu(acc2[ot][et][2]) * mk, fast_silu(acc2[ot][et][3]) * mk);
            *(uint2*)&A[row * 72 + ot * 16 + q * 4] = p;
        }
    }

    // ---- coord mlp ----
    f32x4 acc3[4][4];
    #pragma unroll
    for (int ot = 0; ot < 4; ++ot) {
        const float4 bv = *(const float4*)(bc1 + ot * 16 + q * 4);
        #pragma unroll
        for (int et = 0; et < 4; ++et) {
            acc3[ot][et][0] = bv.x; acc3[ot][et][1] = bv.y;
            acc3[ot][et][2] = bv.z; acc3[ot][et][3] = bv.w;
        }
    }
    #pragma unroll
    for (int ks = 0; ks < 2; ++ks) {
        bf16x8 bfr[4];
        #pragma unroll
        for (int et = 0; et < 4; ++et)
            bfr[et] = *(const bf16x8*)&A[(rbase + et * 16 + lc) * 72 + ks * 32 + q * 8];
        #pragma unroll
        for (int ot = 0; ot < 4; ++ot) {
            const bf16x8 af = *(const bf16x8*)&Wtc1[(ot * 16 + lc) * 64 + ks * 32 + q * 8];
            #pragma unroll
            for (int et = 0; et < 4; ++et)
                acc3[ot][et] = MFMA16(af, bfr[et], acc3[ot][et]);
        }
    }
    {
        float4 wv[4];
        #pragma unroll
        for (int ot = 0; ot < 4; ++ot) wv[ot] = *(const float4*)(Wc2 + ot * 16 + q * 4);
        #pragma unroll
        for (int et = 0; et < 4; ++et) {
            float s = 0.0f;
            #pragma unroll
            for (int ot = 0; ot < 4; ++ot) {
                s = fmaf(fast_silu(acc3[ot][et][0]), wv[ot].x, s);
                s = fmaf(fast_silu(acc3[ot][et][1]), wv[ot].y, s);
                s = fmaf(fast_silu(acc3[ot][et][2]), wv[ot].z, s);
                s = fmaf(fast_silu(acc3[ot][et][3]), wv[ot].w, s);
            }
            s += __shfl_xor(s, 16, 64);
            s += __shfl_xor(s, 32, 64);
            if (q == 0) {
                const int row = rbase + et * 16 + lc;
                cval_s[row] = s * msk_s[row];
            }
        }
    }

    __syncthreads();   // whole block's m / cval / dif now valid

    // ---- fused segmented aggregation ----
    {
        const int n0 = ri_s[0], n1 = ri_s[255];
        for (int n = n0 + w; n <= n1; n += 4) {
            const int os = offs_g[n];
            const int dg = hist_g[n];
            const int s0 = max(os - ebase, 0);
            const int s1 = min(os + dg - ebase, 256);
            float s = 0.0f;
            int slot = s0;
            for (; slot + 4 <= s1; slot += 4) {
                const float a0 = bf16_to_f(A[(slot + 0) * 72 + L]);
                const float a1 = bf16_to_f(A[(slot + 1) * 72 + L]);
                const float a2 = bf16_to_f(A[(slot + 2) * 72 + L]);
                const float a3 = bf16_to_f(A[(slot + 3) * 72 + L]);
                s += (a0 + a1) + (a2 + a3);
            }
            for (; slot < s1; ++slot)
                s += bf16_to_f(A[slot * 72 + L]);
            float t3 = 0.0f;
            if (L < 3) {
                int sl = s0;
                for (; sl + 4 <= s1; sl += 4) {
                    t3 = fmaf(dif_s[(sl + 0) * 3 + L], cval_s[sl + 0], t3);
                    t3 = fmaf(dif_s[(sl + 1) * 3 + L], cval_s[sl + 1], t3);
                    t3 = fmaf(dif_s[(sl + 2) * 3 + L], cval_s[sl + 2], t3);
                    t3 = fmaf(dif_s[(sl + 3) * 3 + L], cval_s[sl + 3], t3);
                }
                for (; sl < s1; ++sl)
                    t3 = fmaf(dif_s[sl * 3 + L], cval_s[sl], t3);
            }
            const bool interior = (os >= ebase) && (os + dg <= ebase + 256);
            if (interior) {
                agg[(size_t)n * 64 + L] = s;
                if (L < 3) aggc[n * 3 + L] = t3;
            } else {
                atomicAdd(&agg[(size_t)n * 64 + L], s);
                if (L < 3) atomicAdd(&aggc[n * 3 + L], t3);
            }
        }
    }
}

// ============================================================================
// node MLP + coord output fused (block-uniform branch)
// ============================================================================
__global__ __launch_bounds__(256, 2) void egcl_node_coord(
    const float* __restrict__ h, const float* __restrict__ agg,
    const float* __restrict__ bn1, const float* __restrict__ bn2,
    const unsigned short* __restrict__ Wtn1, const unsigned short* __restrict__ Wtn2,
    const float* __restrict__ coord, const float* __restrict__ aggc,
    const int* __restrict__ hist,
    float* __restrict__ hout, float* __restrict__ cout)
{
    if (blockIdx.x >= NODE_BLOCKS) {
        const int i = (blockIdx.x - NODE_BLOCKS) * 256 + threadIdx.x;
        if (i < N_NODES * 3) {
            const int node = i / 3;
            const float c = fmaxf((float)hist[node], 1.0f);
            cout[i] = coord[i] + aggc[i] * __builtin_amdgcn_rcpf(c);
        }
        return;
    }

    __shared__ __align__(16) unsigned short A[128 * 136];
    const int t = threadIdx.x;
    const int wave = t >> 6, L = t & 63;
    const int q = L >> 4, lc = L & 15;
    const int nbase = blockIdx.x * 128;
    const int rbase = wave * 32;

    #pragma unroll 4
    for (int it = 0; it < 16; ++it) {
        const int idx = it * 256 + t;
        const int ln = idx >> 5, part = idx & 31;
        const int node = nbase + ln;
        float4 v = make_float4(0.f, 0.f, 0.f, 0.f);
        if (node < N_NODES) {
            v = (part < 16) ? *(const float4*)(h + (size_t)node * 64 + part * 4)
                            : *(const float4*)(agg + (size_t)node * 64 + (part - 16) * 4);
        }
        *(uint2*)&A[ln * 136 + part * 4] = make_uint2(pack_bf2(v.x, v.y), pack_bf2(v.z, v.w));
    }
    __syncthreads();

    f32x4 acc1[2][4];
    #pragma unroll
    for (int ct = 0; ct < 4; ++ct) {
        const float b = bn1[ct * 16 + lc];
        #pragma unroll
        for (int rt = 0; rt < 2; ++rt)
            #pragma unroll
            for (int i = 0; i < 4; ++i) acc1[rt][ct][i] = b;
    }
    #pragma unroll
    for (int ks = 0; ks < 4; ++ks) {
        bf16x8 af[2];
        #pragma unroll
        for (int rt = 0; rt < 2; ++rt)
            af[rt] = *(const bf16x8*)&A[(rbase + rt * 16 + lc) * 136 + ks * 32 + q * 8];
        #pragma unroll
        for (int ct = 0; ct < 4; ++ct) {
            const bf16x8 bf = *(const bf16x8*)&Wtn1[(ct * 16 + lc) * 128 + ks * 32 + q * 8];
            #pragma unroll
            for (int rt = 0; rt < 2; ++rt)
                acc1[rt][ct] = MFMA16(af[rt], bf, acc1[rt][ct]);
        }
    }
    __syncthreads();

    #pragma unroll
    for (int rt = 0; rt < 2; ++rt)
        #pragma unroll
        for (int ct = 0; ct < 4; ++ct)
            #pragma unroll
            for (int i = 0; i < 4; ++i) {
                const int row = rbase + rt * 16 + q * 4 + i;
                A[row * 72 + ct * 16 + lc] = f2bf(fast_silu(acc1[rt][ct][i]));
            }
    __syncthreads();

    f32x4 acc2[2][4];
    #pragma unroll
    for (int ct = 0; ct < 4; ++ct) {
        const float b = bn2[ct * 16 + lc];
        #pragma unroll
        for (int rt = 0; rt < 2; ++rt)
            #pragma unroll
            for (int i = 0; i < 4; ++i) acc2[rt][ct][i] = b;
    }
    #pragma unroll
    for (int ks = 0; ks < 2; ++ks) {
        bf16x8 af[2];
        #pragma unroll
        for (int rt = 0; rt < 2; ++rt)
            af[rt] = *(const bf16x8*)&A[(rbase + rt * 16 + lc) * 72 + ks * 32 + q * 8];
        #pragma unroll
        for (int ct = 0; ct < 4; ++ct) {
            const bf16x8 bf = *(const bf16x8*)&Wtn2[(ct * 16 + lc) * 64 + ks * 32 + q * 8];
            #pragma unroll
            for (int rt = 0; rt < 2; ++rt)
                acc2[rt][ct] = MFMA16(af[rt], bf, acc2[rt][ct]);
        }
    }

    #pragma unroll
    for (int rt = 0; rt < 2; ++rt)
        #pragma unroll
        for (int ct = 0; ct < 4; ++ct)
            #pragma unroll
            for (int i = 0; i < 4; ++i) {
                const int node = nbase + rbase + rt * 16 + q * 4 + i;
                if (node < N_NODES)
                    hout[(size_t)node * 64 + ct * 16 + lc] = acc2[rt][ct][i];
            }
}

// ============================================================================
// launch
// ============================================================================
extern "C" void kernel_launch(void* const* d_in, const int* in_sizes, int n_in,
                              void* d_out, int out_size, void* d_ws, size_t ws_size,
                              hipStream_t stream)
{
    const float* h     = (const float*)d_in[0];
    const float* coord = (const float*)d_in[1];
    const int*   eidx  = (const int*)d_in[2];
    const float* emask = (const float*)d_in[3];
    const float* We1   = (const float*)d_in[4];
    const float* be1   = (const float*)d_in[5];
    const float* We2   = (const float*)d_in[6];
    const float* be2   = (const float*)d_in[7];
    const float* Wn1   = (const float*)d_in[8];
    const float* bn1   = (const float*)d_in[9];
    const float* Wn2   = (const float*)d_in[10];
    const float* bn2   = (const float*)d_in[11];
    const float* Wc1   = (const float*)d_in[12];
    const float* bc1   = (const float*)d_in[13];
    const float* Wc2   = (const float*)d_in[14];

    float* hout = (float*)d_out;
    float* cout = hout + (size_t)N_NODES * 64;

    // ws layout: [agg | aggc | hist] contiguous for one zeroing memset,
    // then CSR arrays, payload, packed inputs, packed weights.
    char* p = (char*)d_ws;
    float* agg  = (float*)p;                      p += (size_t)N_NODES * 64 * 4; // 10.24 MB
    float* aggc = (float*)p;                      p += (size_t)N_NODES * 3 * 4;  // 0.48 MB
    int* hist   = (int*)p;                        p += (size_t)N_NODES * 4;      // 0.16 MB
    int* offs   = (int*)p;                        p += (size_t)N_NODES * 4;
    int* pos    = (int*)p;                        p += (size_t)N_NODES * 4;
    int4* payload = (int4*)p;                     p += (size_t)N_EDGES * 16;     // 20.48 MB
    unsigned short* h_bf = (unsigned short*)p;    p += (size_t)N_NODES * 64 * 2; // 5.12 MB
    unsigned short* Wt1  = (unsigned short*)p;    p += 8192 * 2;
    unsigned short* Wt2  = (unsigned short*)p;    p += 4096 * 2;
    unsigned short* Wtc1 = (unsigned short*)p;    p += 4096 * 2;
    unsigned short* Wtn1 = (unsigned short*)p;    p += 8192 * 2;
    unsigned short* Wtn2 = (unsigned short*)p;    p += 4096 * 2;

    // zero agg + aggc + hist in one shot (10.88 MB)
    hipMemsetAsync(agg, 0, (size_t)N_NODES * 68 * 4, stream);
    prep_hist_kernel<<<3862, 256, 0, stream>>>(h, We1, We2, Wc1, Wn1, Wn2, eidx,
                                               h_bf, Wt1, Wt2, Wtc1, Wtn1, Wtn2, hist);
    scan_kernel<<<1, 1024, 0, stream>>>(hist, offs, pos);
    scatter_kernel<<<N_EDGES / 1024, 256, 0, stream>>>(eidx, emask, pos, payload);
    egcl_edge_mfma<<<N_EDGES / 256, 256, 0, stream>>>(
        h_bf, coord, payload, offs, hist,
        We1, be1, be2, bc1, Wc2, Wt1, Wt2, Wtc1, agg, aggc);
    egcl_node_coord<<<NODE_BLOCKS + (N_NODES * 3 + 255) / 256, 256, 0, stream>>>(
        h, agg, bn1, bn2, Wtn1, Wtn2, coord, aggc, hist, hout, cout);
}

// Round 7
// 416.943 us; speedup vs baseline: 11.7560x; 1.0014x over previous
//
#include <hip/hip_runtime.h>
#include <stdint.h>

#define N_NODES 40000
#define N_EDGES 1280000
#define NODE_BLOCKS 313   // ceil(40000/128)

typedef __attribute__((ext_vector_type(8))) short bf16x8;   // 8 bf16 in 4 VGPRs
typedef __attribute__((ext_vector_type(4))) float f32x4;    // MFMA C/D

#define MFMA16(a, b, c) __builtin_amdgcn_mfma_f32_16x16x32_bf16((a), (b), (c), 0, 0, 0)

// ---------- helpers ----------
__device__ __forceinline__ float fast_silu(float x) {
    float e = __expf(-x);
    return x * __builtin_amdgcn_rcpf(1.0f + e);
}

__device__ __forceinline__ unsigned short f2bf(float x) {
    unsigned int u = __float_as_uint(x);
    u = (u + 0x7FFFu + ((u >> 16) & 1u)) >> 16;
    return (unsigned short)u;
}

__device__ __forceinline__ unsigned int pack_bf2(float a, float b) {
    unsigned int ua = __float_as_uint(a);
    unsigned int ub = __float_as_uint(b);
    ua = (ua + 0x7FFFu + ((ua >> 16) & 1u)) >> 16;
    ub = (ub + 0x7FFFu + ((ub >> 16) & 1u)) & 0xFFFF0000u;
    return (ua & 0xFFFFu) | ub;
}

__device__ __forceinline__ float bf16_to_f(unsigned short s) {
    return __uint_as_float(((unsigned int)s) << 16);
}

// ============================================================================
// prep + hist fused: blocks [0,2500) pack h; [2500,2612) pack weights;
// [2612,3862) histogram rows.
// ============================================================================
__global__ void prep_hist_kernel(const float* __restrict__ h,
                                 const float* __restrict__ We1, const float* __restrict__ We2,
                                 const float* __restrict__ Wc1, const float* __restrict__ Wn1,
                                 const float* __restrict__ Wn2,
                                 const int* __restrict__ eidx,
                                 unsigned short* __restrict__ h_bf,
                                 unsigned short* __restrict__ Wt1, unsigned short* __restrict__ Wt2,
                                 unsigned short* __restrict__ Wtc1, unsigned short* __restrict__ Wtn1,
                                 unsigned short* __restrict__ Wtn2,
                                 int* __restrict__ hist)
{
    const int b = blockIdx.x;
    if (b < 2500) {
        const int i = (b * 256 + threadIdx.x) * 4;   // exactly covers 2,560,000
        const float4 v = *(const float4*)(h + i);
        *(uint2*)(h_bf + i) = make_uint2(pack_bf2(v.x, v.y), pack_bf2(v.z, v.w));
    } else if (b < 2612) {
        const int t = (b - 2500) * 256 + threadIdx.x;
        if (t < 8192)       { Wt1[t]  = f2bf(We1[(t & 127) * 64 + (t >> 7)]); }
        else if (t < 12288) { int u = t - 8192;  Wt2[u]  = f2bf(We2[(u & 63) * 64 + (u >> 6)]); }
        else if (t < 16384) { int u = t - 12288; Wtc1[u] = f2bf(Wc1[(u & 63) * 64 + (u >> 6)]); }
        else if (t < 24576) { int u = t - 16384; Wtn1[u] = f2bf(Wn1[(u & 127) * 64 + (u >> 7)]); }
        else if (t < 28672) { int u = t - 24576; Wtn2[u] = f2bf(Wn2[(u & 63) * 64 + (u >> 6)]); }
    } else {
        const int i = ((b - 2612) * 256 + threadIdx.x) * 4;   // 1250 blocks, exact
        const int4 r = *(const int4*)(eidx + i);
        atomicAdd(&hist[r.x], 1);
        atomicAdd(&hist[r.y], 1);
        atomicAdd(&hist[r.z], 1);
        atomicAdd(&hist[r.w], 1);
    }
}

// ============================================================================
// single-block scan
// ============================================================================
__global__ __launch_bounds__(1024) void scan_kernel(const int* __restrict__ hist,
                                                    int* __restrict__ offs,
                                                    int* __restrict__ pos) {
    __shared__ int wtot[16];
    __shared__ int carry_s;
    const int t = threadIdx.x;
    const int wave = t >> 6, lane = t & 63;
    if (t == 0) carry_s = 0;
    __syncthreads();
    for (int base = 0; base < N_NODES; base += 8192) {
        const int idx = base + t * 8;
        int v[8];
        if (idx + 8 <= N_NODES) {
            const int4 a = *(const int4*)(hist + idx);
            const int4 b = *(const int4*)(hist + idx + 4);
            v[0] = a.x; v[1] = a.y; v[2] = a.z; v[3] = a.w;
            v[4] = b.x; v[5] = b.y; v[6] = b.z; v[7] = b.w;
        } else {
            #pragma unroll
            for (int j = 0; j < 8; ++j) v[j] = (idx + j < N_NODES) ? hist[idx + j] : 0;
        }
        int s = 0;
        #pragma unroll
        for (int j = 0; j < 8; ++j) s += v[j];
        int S = s;
        #pragma unroll
        for (int d = 1; d < 64; d <<= 1) {
            const int u = __shfl_up(S, d, 64);
            if (lane >= d) S += u;
        }
        if (lane == 63) wtot[wave] = S;
        __syncthreads();
        if (wave == 0 && lane < 16) {
            int w = wtot[lane];
            #pragma unroll
            for (int d = 1; d < 16; d <<= 1) {
                const int u = __shfl_up(w, d, 64);
                if (lane >= d) w += u;
            }
            wtot[lane] = w;
        }
        __syncthreads();
        const int wb = (wave == 0) ? 0 : wtot[wave - 1];
        int run = carry_s + wb + (S - s);
        #pragma unroll
        for (int j = 0; j < 8; ++j) {
            if (idx + j < N_NODES) { offs[idx + j] = run; pos[idx + j] = run; }
            run += v[j];
        }
        __syncthreads();
        if (t == 0) carry_s += wtot[15];
        __syncthreads();
    }
}

// ============================================================================
// scatter: one 8 B payload {row|col<<16, mask} per CSR slot
// ============================================================================
__global__ void scatter_kernel(const int* __restrict__ eidx, const float* __restrict__ emask,
                               int* __restrict__ pos, uint2* __restrict__ payload) {
    const int i = (blockIdx.x * 256 + threadIdx.x) * 4;
    const int4 r = *(const int4*)(eidx + i);
    const int4 c = *(const int4*)(eidx + N_EDGES + i);
    const float4 mk = *(const float4*)(emask + i);
    const int s0 = atomicAdd(&pos[r.x], 1);
    payload[s0] = make_uint2((unsigned)r.x | ((unsigned)c.x << 16), __float_as_uint(mk.x));
    const int s1 = atomicAdd(&pos[r.y], 1);
    payload[s1] = make_uint2((unsigned)r.y | ((unsigned)c.y << 16), __float_as_uint(mk.y));
    const int s2 = atomicAdd(&pos[r.z], 1);
    payload[s2] = make_uint2((unsigned)r.z | ((unsigned)c.z << 16), __float_as_uint(mk.z));
    const int s3 = atomicAdd(&pos[r.w], 1);
    payload[s3] = make_uint2((unsigned)r.w | ((unsigned)c.w << 16), __float_as_uint(mk.w));
}

// ============================================================================
// edge kernel: CSR payload, transposed-MFMA, fused aggregation.
// LDS = A(36864) + dif(3072) + cval(1024) = 40960 B exactly -> 4 blocks/CU.
// Per-slot meta (row/col/rad/mask) lives in registers; intra-wave access via
// __shfl. Block node range (n0,n1) stashed in A row-0 padding (shorts 64..67).
// ============================================================================
__global__ __launch_bounds__(256, 4) void egcl_edge_mfma(
    const unsigned short* __restrict__ h_bf, const float* __restrict__ coord,
    const uint2* __restrict__ payload,
    const int* __restrict__ offs_g, const int* __restrict__ hist_g,
    const float* __restrict__ We1, const float* __restrict__ be1,
    const float* __restrict__ be2, const float* __restrict__ bc1,
    const float* __restrict__ Wc2,
    const unsigned short* __restrict__ Wt1, const unsigned short* __restrict__ Wt2,
    const unsigned short* __restrict__ Wtc1,
    float* __restrict__ agg, float* __restrict__ aggc)
{
    __shared__ __align__(16) unsigned short A[256 * 72];
    __shared__ float dif_s[768];
    __shared__ float cval_s[256];

    const int t = threadIdx.x;
    const int w = t >> 6, L = t & 63;
    const int q = L >> 4, lc = L & 15;
    const int ebase = blockIdx.x * 256;
    const int rbase = w * 64;

    // ---- meta: one coalesced 8B payload read per slot; keep in registers ----
    int my_r, my_c;
    float my_rad, my_msk;
    {
        const uint2 pl = payload[ebase + t];
        my_r = (int)(pl.x & 0xFFFFu);
        my_c = (int)(pl.x >> 16);
        my_msk = __uint_as_float(pl.y);
        const float d0 = coord[my_r * 3 + 0] - coord[my_c * 3 + 0];
        const float d1 = coord[my_r * 3 + 1] - coord[my_c * 3 + 1];
        const float d2 = coord[my_r * 3 + 2] - coord[my_c * 3 + 2];
        dif_s[t * 3 + 0] = d0; dif_s[t * 3 + 1] = d1; dif_s[t * 3 + 2] = d2;
        my_rad = d0 * d0 + d1 * d1 + d2 * d2;
        if (t == 0)   *(int*)&A[64] = my_r;   // n0 in row-0 padding
        if (t == 255) *(int*)&A[66] = my_r;   // n1
    }

    // ---- stage h_bf[row] (k = 0..63), wave-private rows via shfl ----
    #pragma unroll
    for (int it = 0; it < 8; ++it) {
        const int rloc = it * 8 + (L >> 3);
        const int part = L & 7;
        const int ridx = __shfl(my_r, rloc, 64);
        const bf16x8 v = *(const bf16x8*)(h_bf + (size_t)ridx * 64 + part * 8);
        *(bf16x8*)&A[(rbase + rloc) * 72 + part * 8] = v;
    }

    // per-et rad / mask via shfl (slot et*16+lc is in this wave)
    float rad_et[4], mk_et[4];
    #pragma unroll
    for (int et = 0; et < 4; ++et) {
        rad_et[et] = __shfl(my_rad, et * 16 + lc, 64);
        mk_et[et]  = __shfl(my_msk, et * 16 + lc, 64);
    }

    // ---- layer1 init ----
    f32x4 acc[4][4];   // [ot][et]
    #pragma unroll
    for (int ot = 0; ot < 4; ++ot) {
        const float4 bv = *(const float4*)(be1 + ot * 16 + q * 4);
        const float4 wv = *(const float4*)(We1 + 128 * 64 + ot * 16 + q * 4);
        #pragma unroll
        for (int et = 0; et < 4; ++et) {
            const float rad = rad_et[et];
            acc[ot][et][0] = fmaf(rad, wv.x, bv.x);
            acc[ot][et][1] = fmaf(rad, wv.y, bv.y);
            acc[ot][et][2] = fmaf(rad, wv.z, bv.z);
            acc[ot][et][3] = fmaf(rad, wv.w, bv.w);
        }
    }

    // ---- layer1 MFMA, k = 0..63 (h[row]) ----
    #pragma unroll
    for (int ks = 0; ks < 2; ++ks) {
        bf16x8 bfr[4];
        #pragma unroll
        for (int et = 0; et < 4; ++et)
            bfr[et] = *(const bf16x8*)&A[(rbase + et * 16 + lc) * 72 + ks * 32 + q * 8];
        #pragma unroll
        for (int ot = 0; ot < 4; ++ot) {
            const bf16x8 af = *(const bf16x8*)&Wt1[(ot * 16 + lc) * 128 + ks * 32 + q * 8];
            #pragma unroll
            for (int et = 0; et < 4; ++et)
                acc[ot][et] = MFMA16(af, bfr[et], acc[ot][et]);
        }
    }

    // ---- restage h_bf[col] ----
    #pragma unroll
    for (int it = 0; it < 8; ++it) {
        const int rloc = it * 8 + (L >> 3);
        const int part = L & 7;
        const int cidx = __shfl(my_c, rloc, 64);
        const bf16x8 v = *(const bf16x8*)(h_bf + (size_t)cidx * 64 + part * 8);
        *(bf16x8*)&A[(rbase + rloc) * 72 + part * 8] = v;
    }

    // ---- layer1 MFMA, k = 64..127 (h[col]) ----
    #pragma unroll
    for (int ks = 0; ks < 2; ++ks) {
        bf16x8 bfr[4];
        #pragma unroll
        for (int et = 0; et < 4; ++et)
            bfr[et] = *(const bf16x8*)&A[(rbase + et * 16 + lc) * 72 + ks * 32 + q * 8];
        #pragma unroll
        for (int ot = 0; ot < 4; ++ot) {
            const bf16x8 af = *(const bf16x8*)&Wt1[(ot * 16 + lc) * 128 + 64 + ks * 32 + q * 8];
            #pragma unroll
            for (int et = 0; et < 4; ++et)
                acc[ot][et] = MFMA16(af, bfr[et], acc[ot][et]);
        }
    }

    // ---- m1 = silu -> A ----
    #pragma unroll
    for (int et = 0; et < 4; ++et) {
        const int row = rbase + et * 16 + lc;
        #pragma unroll
        for (int ot = 0; ot < 4; ++ot) {
            uint2 p;
            p.x = pack_bf2(fast_silu(acc[ot][et][0]), fast_silu(acc[ot][et][1]));
            p.y = pack_bf2(fast_silu(acc[ot][et][2]), fast_silu(acc[ot][et][3]));
            *(uint2*)&A[row * 72 + ot * 16 + q * 4] = p;
        }
    }

    // ---- layer2 ----
    f32x4 acc2[4][4];
    #pragma unroll
    for (int ot = 0; ot < 4; ++ot) {
        const float4 bv = *(const float4*)(be2 + ot * 16 + q * 4);
        #pragma unroll
        for (int et = 0; et < 4; ++et) {
            acc2[ot][et][0] = bv.x; acc2[ot][et][1] = bv.y;
            acc2[ot][et][2] = bv.z; acc2[ot][et][3] = bv.w;
        }
    }
    #pragma unroll
    for (int ks = 0; ks < 2; ++ks) {
        bf16x8 bfr[4];
        #pragma unroll
        for (int et = 0; et < 4; ++et)
            bfr[et] = *(const bf16x8*)&A[(rbase + et * 16 + lc) * 72 + ks * 32 + q * 8];
        #pragma unroll
        for (int ot = 0; ot < 4; ++ot) {
            const bf16x8 af = *(const bf16x8*)&Wt2[(ot * 16 + lc) * 64 + ks * 32 + q * 8];
            #pragma unroll
            for (int et = 0; et < 4; ++et)
                acc2[ot][et] = MFMA16(af, bfr[et], acc2[ot][et]);
        }
    }

    // ---- m = silu * mask -> A ----
    #pragma unroll
    for (int et = 0; et < 4; ++et) {
        const int row = rbase + et * 16 + lc;
        const float mk = mk_et[et];
        #pragma unroll
        for (int ot = 0; ot < 4; ++ot) {
            uint2 p;
            p.x = pack_bf2(fast_silu(acc2[ot][et][0]) * mk, fast_silu(acc2[ot][et][1]) * mk);
            p.y = pack_bf2(fast_silu(acc2[ot][et][2]) * mk, fast_silu(acc2[ot][et][3]) * mk);
            *(uint2*)&A[row * 72 + ot * 16 + q * 4] = p;
        }
    }

    // ---- coord mlp ----
    f32x4 acc3[4][4];
    #pragma unroll
    for (int ot = 0; ot < 4; ++ot) {
        const float4 bv = *(const float4*)(bc1 + ot * 16 + q * 4);
        #pragma unroll
        for (int et = 0; et < 4; ++et) {
            acc3[ot][et][0] = bv.x; acc3[ot][et][1] = bv.y;
            acc3[ot][et][2] = bv.z; acc3[ot][et][3] = bv.w;
        }
    }
    #pragma unroll
    for (int ks = 0; ks < 2; ++ks) {
        bf16x8 bfr[4];
        #pragma unroll
        for (int et = 0; et < 4; ++et)
            bfr[et] = *(const bf16x8*)&A[(rbase + et * 16 + lc) * 72 + ks * 32 + q * 8];
        #pragma unroll
        for (int ot = 0; ot < 4; ++ot) {
            const bf16x8 af = *(const bf16x8*)&Wtc1[(ot * 16 + lc) * 64 + ks * 32 + q * 8];
            #pragma unroll
            for (int et = 0; et < 4; ++et)
                acc3[ot][et] = MFMA16(af, bfr[et], acc3[ot][et]);
        }
    }
    {
        float4 wv[4];
        #pragma unroll
        for (int ot = 0; ot < 4; ++ot) wv[ot] = *(const float4*)(Wc2 + ot * 16 + q * 4);
        #pragma unroll
        for (int et = 0; et < 4; ++et) {
            float s = 0.0f;
            #pragma unroll
            for (int ot = 0; ot < 4; ++ot) {
                s = fmaf(fast_silu(acc3[ot][et][0]), wv[ot].x, s);
                s = fmaf(fast_silu(acc3[ot][et][1]), wv[ot].y, s);
                s = fmaf(fast_silu(acc3[ot][et][2]), wv[ot].z, s);
                s = fmaf(fast_silu(acc3[ot][et][3]), wv[ot].w, s);
            }
            s += __shfl_xor(s, 16, 64);
            s += __shfl_xor(s, 32, 64);
            if (q == 0)
                cval_s[rbase + et * 16 + lc] = s * mk_et[et];
        }
    }

    __syncthreads();   // whole block's m / cval / dif now valid

    // ---- fused segmented aggregation (merged m + t3 slot loop) ----
    {
        const int n0 = *(const int*)&A[64];
        const int n1 = *(const int*)&A[66];
        for (int n = n0 + w; n <= n1; n += 4) {
            const int os = offs_g[n];
            const int dg = hist_g[n];
            const int s0 = max(os - ebase, 0);
            const int s1 = min(os + dg - ebase, 256);
            float s = 0.0f, t3 = 0.0f;
            const bool c3 = (L < 3);
            int slot = s0;
            for (; slot + 4 <= s1; slot += 4) {
                const float a0 = bf16_to_f(A[(slot + 0) * 72 + L]);
                const float a1 = bf16_to_f(A[(slot + 1) * 72 + L]);
                const float a2 = bf16_to_f(A[(slot + 2) * 72 + L]);
                const float a3 = bf16_to_f(A[(slot + 3) * 72 + L]);
                s += (a0 + a1) + (a2 + a3);
                if (c3) {
                    t3 = fmaf(dif_s[(slot + 0) * 3 + L], cval_s[slot + 0], t3);
                    t3 = fmaf(dif_s[(slot + 1) * 3 + L], cval_s[slot + 1], t3);
                    t3 = fmaf(dif_s[(slot + 2) * 3 + L], cval_s[slot + 2], t3);
                    t3 = fmaf(dif_s[(slot + 3) * 3 + L], cval_s[slot + 3], t3);
                }
            }
            for (; slot < s1; ++slot) {
                s += bf16_to_f(A[slot * 72 + L]);
                if (c3) t3 = fmaf(dif_s[slot * 3 + L], cval_s[slot], t3);
            }
            const bool interior = (os >= ebase) && (os + dg <= ebase + 256);
            if (interior) {
                agg[(size_t)n * 64 + L] = s;
                if (c3) aggc[n * 3 + L] = t3;
            } else {
                atomicAdd(&agg[(size_t)n * 64 + L], s);
                if (c3) atomicAdd(&aggc[n * 3 + L], t3);
            }
        }
    }
}

// ============================================================================
// node MLP + coord output fused (block-uniform branch)
// ============================================================================
__global__ __launch_bounds__(256, 2) void egcl_node_coord(
    const float* __restrict__ h, const float* __restrict__ agg,
    const float* __restrict__ bn1, const float* __restrict__ bn2,
    const unsigned short* __restrict__ Wtn1, const unsigned short* __restrict__ Wtn2,
    const float* __restrict__ coord, const float* __restrict__ aggc,
    const int* __restrict__ hist,
    float* __restrict__ hout, float* __restrict__ cout)
{
    if (blockIdx.x >= NODE_BLOCKS) {
        const int i = (blockIdx.x - NODE_BLOCKS) * 256 + threadIdx.x;
        if (i < N_NODES * 3) {
            const int node = i / 3;
            const float c = fmaxf((float)hist[node], 1.0f);
            cout[i] = coord[i] + aggc[i] * __builtin_amdgcn_rcpf(c);
        }
        return;
    }

    __shared__ __align__(16) unsigned short A[128 * 136];
    const int t = threadIdx.x;
    const int wave = t >> 6, L = t & 63;
    const int q = L >> 4, lc = L & 15;
    const int nbase = blockIdx.x * 128;
    const int rbase = wave * 32;

    #pragma unroll 4
    for (int it = 0; it < 16; ++it) {
        const int idx = it * 256 + t;
        const int ln = idx >> 5, part = idx & 31;
        const int node = nbase + ln;
        float4 v = make_float4(0.f, 0.f, 0.f, 0.f);
        if (node < N_NODES) {
            v = (part < 16) ? *(const float4*)(h + (size_t)node * 64 + part * 4)
                            : *(const float4*)(agg + (size_t)node * 64 + (part - 16) * 4);
        }
        *(uint2*)&A[ln * 136 + part * 4] = make_uint2(pack_bf2(v.x, v.y), pack_bf2(v.z, v.w));
    }
    __syncthreads();

    f32x4 acc1[2][4];
    #pragma unroll
    for (int ct = 0; ct < 4; ++ct) {
        const float b = bn1[ct * 16 + lc];
        #pragma unroll
        for (int rt = 0; rt < 2; ++rt)
            #pragma unroll
            for (int i = 0; i < 4; ++i) acc1[rt][ct][i] = b;
    }
    #pragma unroll
    for (int ks = 0; ks < 4; ++ks) {
        bf16x8 af[2];
        #pragma unroll
        for (int rt = 0; rt < 2; ++rt)
            af[rt] = *(const bf16x8*)&A[(rbase + rt * 16 + lc) * 136 + ks * 32 + q * 8];
        #pragma unroll
        for (int ct = 0; ct < 4; ++ct) {
            const bf16x8 bf = *(const bf16x8*)&Wtn1[(ct * 16 + lc) * 128 + ks * 32 + q * 8];
            #pragma unroll
            for (int rt = 0; rt < 2; ++rt)
                acc1[rt][ct] = MFMA16(af[rt], bf, acc1[rt][ct]);
        }
    }
    __syncthreads();

    #pragma unroll
    for (int rt = 0; rt < 2; ++rt)
        #pragma unroll
        for (int ct = 0; ct < 4; ++ct)
            #pragma unroll
            for (int i = 0; i < 4; ++i) {
                const int row = rbase + rt * 16 + q * 4 + i;
                A[row * 72 + ct * 16 + lc] = f2bf(fast_silu(acc1[rt][ct][i]));
            }
    __syncthreads();

    f32x4 acc2[2][4];
    #pragma unroll
    for (int ct = 0; ct < 4; ++ct) {
        const float b = bn2[ct * 16 + lc];
        #pragma unroll
        for (int rt = 0; rt < 2; ++rt)
            #pragma unroll
            for (int i = 0; i < 4; ++i) acc2[rt][ct][i] = b;
    }
    #pragma unroll
    for (int ks = 0; ks < 2; ++ks) {
        bf16x8 af[2];
        #pragma unroll
        for (int rt = 0; rt < 2; ++rt)
            af[rt] = *(const bf16x8*)&A[(rbase + rt * 16 + lc) * 72 + ks * 32 + q * 8];
        #pragma unroll
        for (int ct = 0; ct < 4; ++ct) {
            const bf16x8 bf = *(const bf16x8*)&Wtn2[(ct * 16 + lc) * 64 + ks * 32 + q * 8];
            #pragma unroll
            for (int rt = 0; rt < 2; ++rt)
                acc2[rt][ct] = MFMA16(af[rt], bf, acc2[rt][ct]);
        }
    }

    #pragma unroll
    for (int rt = 0; rt < 2; ++rt)
        #pragma unroll
        for (int ct = 0; ct < 4; ++ct)
            #pragma unroll
            for (int i = 0; i < 4; ++i) {
                const int node = nbase + rbase + rt * 16 + q * 4 + i;
                if (node < N_NODES)
                    hout[(size_t)node * 64 + ct * 16 + lc] = acc2[rt][ct][i];
            }
}

// ============================================================================
// launch
// ============================================================================
extern "C" void kernel_launch(void* const* d_in, const int* in_sizes, int n_in,
                              void* d_out, int out_size, void* d_ws, size_t ws_size,
                              hipStream_t stream)
{
    const float* h     = (const float*)d_in[0];
    const float* coord = (const float*)d_in[1];
    const int*   eidx  = (const int*)d_in[2];
    const float* emask = (const float*)d_in[3];
    const float* We1   = (const float*)d_in[4];
    const float* be1   = (const float*)d_in[5];
    const float* We2   = (const float*)d_in[6];
    const float* be2   = (const float*)d_in[7];
    const float* Wn1   = (const float*)d_in[8];
    const float* bn1   = (const float*)d_in[9];
    const float* Wn2   = (const float*)d_in[10];
    const float* bn2   = (const float*)d_in[11];
    const float* Wc1   = (const float*)d_in[12];
    const float* bc1   = (const float*)d_in[13];
    const float* Wc2   = (const float*)d_in[14];

    float* hout = (float*)d_out;
    float* cout = hout + (size_t)N_NODES * 64;

    // ws layout: [agg | aggc | hist] contiguous for one zeroing memset,
    // then CSR arrays, payload, packed inputs, packed weights.
    char* p = (char*)d_ws;
    float* agg  = (float*)p;                      p += (size_t)N_NODES * 64 * 4; // 10.24 MB
    float* aggc = (float*)p;                      p += (size_t)N_NODES * 3 * 4;  // 0.48 MB
    int* hist   = (int*)p;                        p += (size_t)N_NODES * 4;      // 0.16 MB
    int* offs   = (int*)p;                        p += (size_t)N_NODES * 4;
    int* pos    = (int*)p;                        p += (size_t)N_NODES * 4;
    uint2* payload = (uint2*)p;                   p += (size_t)N_EDGES * 8;      // 10.24 MB
    unsigned short* h_bf = (unsigned short*)p;    p += (size_t)N_NODES * 64 * 2; // 5.12 MB
    unsigned short* Wt1  = (unsigned short*)p;    p += 8192 * 2;
    unsigned short* Wt2  = (unsigned short*)p;    p += 4096 * 2;
    unsigned short* Wtc1 = (unsigned short*)p;    p += 4096 * 2;
    unsigned short* Wtn1 = (unsigned short*)p;    p += 8192 * 2;
    unsigned short* Wtn2 = (unsigned short*)p;    p += 4096 * 2;

    // zero agg + aggc + hist in one shot (10.88 MB)
    hipMemsetAsync(agg, 0, (size_t)N_NODES * 68 * 4, stream);
    prep_hist_kernel<<<3862, 256, 0, stream>>>(h, We1, We2, Wc1, Wn1, Wn2, eidx,
                                               h_bf, Wt1, Wt2, Wtc1, Wtn1, Wtn2, hist);
    scan_kernel<<<1, 1024, 0, stream>>>(hist, offs, pos);
    scatter_kernel<<<N_EDGES / 1024, 256, 0, stream>>>(eidx, emask, pos, payload);
    egcl_edge_mfma<<<N_EDGES / 256, 256, 0, stream>>>(
        h_bf, coord, payload, offs, hist,
        We1, be1, be2, bc1, Wc2, Wt1, Wt2, Wtc1, agg, aggc);
    egcl_node_coord<<<NODE_BLOCKS + (N_NODES * 3 + 255) / 256, 256, 0, stream>>>(
        h, agg, bn1, bn2, Wtn1, Wtn2, coord, aggc, hist, hout, cout);
}